// Round 2
// baseline (3266.280 us; speedup 1.0000x reference)
//
#include <hip/hip_runtime.h>
#include <cstdint>
#include <cstddef>

#define M_TOK   1232      // B*S
#define M_PAD   1280
#define D_MODEL 2048
#define F_FFN   8192
#define SEQ     77
#define BATCH   16
#define NHEAD   16
#define LRANK   16
#define NLAYER  2

typedef short bf16x8 __attribute__((ext_vector_type(8)));
typedef float f32x4  __attribute__((ext_vector_type(4)));

__device__ __constant__ float NF4C[16] = {
  -1.0f, -0.6961928009986877f, -0.5250730514526367f, -0.39491748809814453f,
  -0.28444138169288635f, -0.18477343022823334f, -0.09105003625154495f, 0.0f,
  0.07958029955625534f, 0.16093020141124725f, 0.24611230194568634f,
  0.33791524171829224f, 0.44070982933044434f, 0.5626170039176941f,
  0.723855197429657f, 1.0f };

__device__ inline unsigned short f2b(float f) {
  unsigned u = __builtin_bit_cast(unsigned, f);
  u += 0x7FFFu + ((u >> 16) & 1u);   // RNE
  return (unsigned short)(u >> 16);
}
__device__ inline float b2f(unsigned short s) {
  return __builtin_bit_cast(float, ((unsigned)s) << 16);
}

// ---------------------------------------------------------------------------
// Fused NF4-dequant GEMM: O[M][N] (+)= X[M][K] @ W^T
// BM=BN=128, BK=64 (= absmax block). 4 waves 2x2, each wave 64x64 via 4x4
// 16x16x32 bf16 MFMA. X staged via global_load_lds (pre-swizzled source);
// W dequantized through a 256-entry bf16-pair table, scale applied per K-tile
// in f32. Both LDS tiles XOR-swizzled (slot ^= row&7).
// ---------------------------------------------------------------------------
__global__ __launch_bounds__(256, 2) void gemm_dq(
    const unsigned short* __restrict__ X, const int* __restrict__ C,
    const float* __restrict__ AM, float* __restrict__ O,
    int mb, int N, int K, int acc_mode)
{
  __shared__ unsigned short xs[128 * 64];
  __shared__ unsigned short wsL[128 * 64];
  __shared__ unsigned int   tbl[256];
  __shared__ float          amL[128];

  int tid = threadIdx.x;
  { // packed bf16 pair table: entry[(hi<<4)|lo] = (b(NF4[hi])<<16)|b(NF4[lo])
    int hi = tid >> 4, lo = tid & 15;
    tbl[tid] = ((unsigned)f2b(NF4C[hi]) << 16) | (unsigned)f2b(NF4C[lo]);
  }

  // XCD-chunked bijective swizzle: consecutive wgid (same weight panel) on one XCD
  int nwg = gridDim.x;
  int q8 = nwg >> 3, r8 = nwg & 7;
  int xcd = blockIdx.x & 7, pos = blockIdx.x >> 3;
  int wgid = (xcd < r8) ? (xcd * (q8 + 1) + pos)
                        : (r8 * (q8 + 1) + (xcd - r8) * q8 + pos);
  int mblk = wgid % mb, nblk = wgid / mb;
  int row0 = mblk * 128, col0 = nblk * 128;

  int wave = tid >> 6, lane = tid & 63;
  int fr = lane & 15, fg = lane >> 4, s7 = fr & 7;
  int wm = (wave >> 1) * 64, wn = (wave & 1) * 64;

  // W staging: thread -> (row, 32-col segment)
  int srow = tid >> 1;
  int kseg = (tid & 1) * 32;
  int n7 = srow & 7;
  // X staging: per-lane pre-swizzled source column (bf16 elems)
  int xcol = (((lane & 7) ^ ((lane >> 3) & 7)) << 3);

  const int KB = K >> 6;

  f32x4 accm[4][4];
  #pragma unroll
  for (int i = 0; i < 4; ++i)
    #pragma unroll
    for (int j = 0; j < 4; ++j) accm[i][j] = (f32x4){0.f, 0.f, 0.f, 0.f};

  __syncthreads();  // tbl ready

  for (int kt = 0; kt < KB; ++kt) {
    // ---- stage X: 16 chunks of 1KB via global_load_lds (linear dest) ----
    const unsigned short* xbase = X + (size_t)row0 * K + (size_t)kt * 64;
    #pragma unroll
    for (int p = 0; p < 4; ++p) {
      int c = wave * 4 + p;
      int row = c * 8 + (lane >> 3);
      const unsigned short* gp = xbase + (size_t)row * K + xcol;
      __builtin_amdgcn_global_load_lds(
          (const __attribute__((address_space(1))) unsigned int*)gp,
          (__attribute__((address_space(3))) unsigned int*)(xs + c * 512),
          16, 0, 0);
    }
    // ---- stage W: 32 codes/thread -> 4 swizzled b128 writes ----
    {
      const int4* cp = (const int4*)(C + (size_t)(col0 + srow) * K
                                       + (size_t)kt * 64 + kseg);
      unsigned short* wrow = wsL + srow * 64;
      #pragma unroll
      for (int h = 0; h < 4; ++h) {
        int4 ca = cp[2 * h], cb = cp[2 * h + 1];
        uint4 pk;
        pk.x = tbl[(ca.y << 4) | ca.x];
        pk.y = tbl[(ca.w << 4) | ca.z];
        pk.z = tbl[(cb.y << 4) | cb.x];
        pk.w = tbl[(cb.w << 4) | cb.z];
        int slot = (kseg >> 3) + h;           // 0..7
        *(uint4*)(wrow + ((slot ^ n7) << 3)) = pk;
      }
    }
    if (tid < 128) amL[tid] = AM[(size_t)(col0 + tid) * KB + kt];

    __syncthreads();

    // ---- compute: unscaled tile acc, then f32 scale-accumulate ----
    f32x4 acct[4][4];
    {
      bf16x8 af[4], bfr[4];
      #pragma unroll
      for (int mi = 0; mi < 4; ++mi) {
        int row = wm + mi * 16 + fr;
        af[mi] = *(const bf16x8*)(xs + row * 64 + ((fg ^ s7) << 3));
      }
      #pragma unroll
      for (int ni = 0; ni < 4; ++ni) {
        int row = wn + ni * 16 + fr;
        bfr[ni] = *(const bf16x8*)(wsL + row * 64 + ((fg ^ s7) << 3));
      }
      #pragma unroll
      for (int mi = 0; mi < 4; ++mi)
        #pragma unroll
        for (int ni = 0; ni < 4; ++ni)
          acct[mi][ni] = __builtin_amdgcn_mfma_f32_16x16x32_bf16(
              af[mi], bfr[ni], (f32x4){0.f, 0.f, 0.f, 0.f}, 0, 0, 0);
    }
    {
      bf16x8 af[4], bfr[4];
      #pragma unroll
      for (int mi = 0; mi < 4; ++mi) {
        int row = wm + mi * 16 + fr;
        af[mi] = *(const bf16x8*)(xs + row * 64 + (((4 | fg) ^ s7) << 3));
      }
      #pragma unroll
      for (int ni = 0; ni < 4; ++ni) {
        int row = wn + ni * 16 + fr;
        bfr[ni] = *(const bf16x8*)(wsL + row * 64 + (((4 | fg) ^ s7) << 3));
      }
      #pragma unroll
      for (int mi = 0; mi < 4; ++mi)
        #pragma unroll
        for (int ni = 0; ni < 4; ++ni)
          acct[mi][ni] = __builtin_amdgcn_mfma_f32_16x16x32_bf16(
              af[mi], bfr[ni], acct[mi][ni], 0, 0, 0);
    }
    float amv[4];
    #pragma unroll
    for (int ni = 0; ni < 4; ++ni) amv[ni] = amL[wn + ni * 16 + fr];
    #pragma unroll
    for (int mi = 0; mi < 4; ++mi)
      #pragma unroll
      for (int ni = 0; ni < 4; ++ni)
        accm[mi][ni] += amv[ni] * acct[mi][ni];

    __syncthreads();
  }

  // ---- epilogue ----
  #pragma unroll
  for (int mi = 0; mi < 4; ++mi)
    #pragma unroll
    for (int ni = 0; ni < 4; ++ni) {
      int gm0 = row0 + wm + mi * 16 + fg * 4;
      int gn = col0 + wn + ni * 16 + fr;
      #pragma unroll
      for (int r = 0; r < 4; ++r) {
        int gm = gm0 + r;
        if (gm < M_TOK) {
          size_t idx = (size_t)gm * N + gn;
          float vv = accm[mi][ni][r];
          O[idx] = acc_mode ? (O[idx] + vv) : vv;
        }
      }
    }
}

// ---------------------------------------------------------------------------
// LoRA stage 1: T[m][bi*16+g] = sum_k X[m][k] * A[bi][g][k]  (bf16 x)
__global__ __launch_bounds__(256) void lora1(
    const unsigned short* __restrict__ X, const float* __restrict__ A,
    float* __restrict__ T, int K)
{
  int m = blockIdx.x, bi = blockIdx.y, nmat = gridDim.y;
  int g = threadIdx.x >> 4, l16 = threadIdx.x & 15;
  const unsigned short* xr = X + (size_t)m * K;
  const float* ar = A + (size_t)bi * LRANK * K + (size_t)g * K;
  float s = 0.f;
  for (int kk = l16; kk < K; kk += 16) s += b2f(xr[kk]) * ar[kk];
  #pragma unroll
  for (int off = 8; off; off >>= 1) s += __shfl_down(s, off, 16);
  if (l16 == 0) T[(size_t)m * nmat * LRANK + bi * LRANK + g] = s;
}

// LoRA stage 2: O[m][n] += 2 * sum_r T[m][(n>>sh)*16+r] * Bm[n][r]
__global__ __launch_bounds__(256) void lora2(
    float* __restrict__ O, const float* __restrict__ T,
    const float* __restrict__ Bm, int N, int sh, int nr)
{
  int m = blockIdx.y;
  int n = blockIdx.x * 256 + threadIdx.x;
  __shared__ float ts[48];
  if (threadIdx.x < nr) ts[threadIdx.x] = T[(size_t)m * nr + threadIdx.x];
  __syncthreads();
  const float* tsb = ts + ((n >> sh) << 4);
  const float4* br = (const float4*)(Bm + (size_t)n * LRANK);
  float s = 0.f;
  #pragma unroll
  for (int v2 = 0; v2 < 4; ++v2) {
    float4 b = br[v2];
    s += b.x * tsb[v2*4+0] + b.y * tsb[v2*4+1] + b.z * tsb[v2*4+2] + b.w * tsb[v2*4+3];
  }
  O[(size_t)m * N + n] += 2.0f * s;
}

// ---------------------------------------------------------------------------
__global__ __launch_bounds__(256) void rmsnorm_k(
    const float* __restrict__ H, const float* __restrict__ W,
    unsigned short* __restrict__ X, int D)
{
  int m = blockIdx.x;
  const float* hr = H + (size_t)m * D;
  float s = 0.f;
  for (int i = threadIdx.x; i < D; i += 256) { float v = hr[i]; s += v * v; }
  __shared__ float red[4];
  #pragma unroll
  for (int off = 32; off; off >>= 1) s += __shfl_down(s, off, 64);
  if ((threadIdx.x & 63) == 0) red[threadIdx.x >> 6] = s;
  __syncthreads();
  float tot = red[0] + red[1] + red[2] + red[3];
  float inv = rsqrtf(tot / (float)D + 1e-6f);
  for (int i = threadIdx.x; i < D; i += 256)
    X[(size_t)m * D + i] = f2b(hr[i] * inv * W[i]);
}

__global__ void rope_table(float* __restrict__ cosT, float* __restrict__ sinT)
{
  int idx = blockIdx.x * 64 + threadIdx.x;
  if (idx >= SEQ * 64) return;
  int s = idx >> 6, j = idx & 63;
  float inv = powf(10000.0f, -(float)(2 * j) / 128.0f);
  float f = (float)s * inv;
  cosT[idx] = cosf(f);
  sinT[idx] = sinf(f);
}

// QKV packed buffer: row stride 6144; q at +0, k at +2048
__global__ void rope_apply(float* __restrict__ QKV,
                           const float* __restrict__ cosT, const float* __restrict__ sinT)
{
  size_t idx = (size_t)blockIdx.x * 256 + threadIdx.x;
  if (idx >= (size_t)M_TOK * NHEAD * 64) return;
  int j = (int)(idx & 63);
  int h = (int)((idx >> 6) & (NHEAD - 1));
  int m = (int)(idx >> 10);
  int s = m % SEQ;
  float c = cosT[s * 64 + j], sn = sinT[s * 64 + j];
  size_t base = (size_t)m * (3 * D_MODEL) + h * 128;
  float q1 = QKV[base + j], q2 = QKV[base + 64 + j];
  QKV[base + j]      = q1 * c - q2 * sn;
  QKV[base + 64 + j] = q2 * c + q1 * sn;
  size_t kb = base + D_MODEL;
  float k1 = QKV[kb + j], k2 = QKV[kb + 64 + j];
  QKV[kb + j]      = k1 * c - k2 * sn;
  QKV[kb + 64 + j] = k2 * c + k1 * sn;
}

__global__ __launch_bounds__(256) void attn_k(
    const float* __restrict__ QKV, const int* __restrict__ amask,
    unsigned short* __restrict__ O)
{
  int bh = blockIdx.x;
  int b = bh / NHEAD, h = bh % NHEAD;
  __shared__ float sc[SEQ * SEQ];
  const float scale = 0.08838834764831845f;  // 1/sqrt(128)
  const int STR = 3 * D_MODEL;
  for (int idx = threadIdx.x; idx < SEQ * SEQ; idx += 256) {
    int i = idx / SEQ, j = idx % SEQ;
    float val = -1e9f;
    if (j <= i && amask[b * SEQ + j] != 0) {
      const float4* qr = (const float4*)(QKV + (size_t)(b*SEQ+i) * STR + h*128);
      const float4* kr = (const float4*)(QKV + (size_t)(b*SEQ+j) * STR + D_MODEL + h*128);
      float s = 0.f;
      #pragma unroll 8
      for (int d = 0; d < 32; ++d) {
        float4 a = qr[d], c = kr[d];
        s += a.x*c.x + a.y*c.y + a.z*c.z + a.w*c.w;
      }
      val = s * scale;
    }
    sc[idx] = val;
  }
  __syncthreads();
  for (int i = threadIdx.x; i < SEQ; i += 256) {
    float mx = -1e30f;
    for (int j = 0; j < SEQ; ++j) mx = fmaxf(mx, sc[i*SEQ+j]);
    float sum = 0.f;
    for (int j = 0; j < SEQ; ++j) { float e = expf(sc[i*SEQ+j] - mx); sc[i*SEQ+j] = e; sum += e; }
    float inv = 1.0f / sum;
    for (int j = 0; j < SEQ; ++j) sc[i*SEQ+j] *= inv;
  }
  __syncthreads();
  for (int idx = threadIdx.x; idx < SEQ * 128; idx += 256) {
    int i = idx >> 7, d = idx & 127;
    float s = 0.f;
    for (int j = 0; j < SEQ; ++j)
      s += sc[i*SEQ+j] * QKV[(size_t)(b*SEQ+j) * STR + 2*D_MODEL + h*128 + d];
    O[(size_t)(b*SEQ+i) * D_MODEL + h*128 + d] = f2b(s);
  }
}

__global__ void embed_gather(const float* __restrict__ E, const int* __restrict__ ids,
                             float* __restrict__ H)
{
  size_t idx = (size_t)blockIdx.x * 256 + threadIdx.x;
  int m = (int)(idx / D_MODEL);
  int n = (int)(idx % D_MODEL);
  H[idx] = E[(size_t)ids[m] * D_MODEL + n];
}

// GU packed buffer: row stride 16384; g at +0, up at +8192. Output bf16.
__global__ void silu_mul(const float* __restrict__ GU, unsigned short* __restrict__ GB)
{
  size_t id = (size_t)blockIdx.x * 256 + threadIdx.x;
  int m = (int)(id >> 13), n = (int)(id & (F_FFN - 1));
  float g = GU[(size_t)m * 2 * F_FFN + n];
  float u = GU[(size_t)m * 2 * F_FFN + F_FFN + n];
  float sig = 1.0f / (1.0f + expf(-g));
  GB[id] = f2b(g * sig * u);
}

__global__ __launch_bounds__(256) void final_k(
    const float* __restrict__ H, const int* __restrict__ amask,
    const float* __restrict__ W, float* __restrict__ out)
{
  int b = blockIdx.x;
  __shared__ int len;
  if (threadIdx.x == 0) {
    int s = 0;
    for (int j = 0; j < SEQ; ++j) s += amask[b * SEQ + j];
    len = s - 1;
  }
  __syncthreads();
  const float* hr = H + ((size_t)(b * SEQ + len) * D_MODEL);
  float s = 0.f;
  for (int i = threadIdx.x; i < D_MODEL; i += 256) { float v = hr[i]; s += v * v; }
  __shared__ float red[4];
  #pragma unroll
  for (int off = 32; off; off >>= 1) s += __shfl_down(s, off, 64);
  if ((threadIdx.x & 63) == 0) red[threadIdx.x >> 6] = s;
  __syncthreads();
  float tot = red[0] + red[1] + red[2] + red[3];
  float inv = rsqrtf(tot / (float)D_MODEL + 1e-6f);
  for (int i = threadIdx.x; i < D_MODEL; i += 256)
    out[(size_t)b * D_MODEL + i] = hr[i] * inv * W[i];
}

// ---------------------------------------------------------------------------
extern "C" void kernel_launch(void* const* d_in, const int* in_sizes, int n_in,
                              void* d_out, int out_size, void* d_ws, size_t ws_size,
                              hipStream_t stream) {
  const int*   ids     = (const int*)d_in[0];
  const int*   amask   = (const int*)d_in[1];
  const float* embed   = (const float*)d_in[2];
  const float* ln_attn = (const float*)d_in[3];
  const float* ln_mlp  = (const float*)d_in[4];
  const float* ln_fin  = (const float*)d_in[5];
  const int*   qkvC    = (const int*)d_in[6];
  const float* qkvS    = (const float*)d_in[7];
  const float* qkvA    = (const float*)d_in[8];
  const float* qkvB    = (const float*)d_in[9];
  const int*   oC      = (const int*)d_in[10];
  const float* oS      = (const float*)d_in[11];
  const float* oA      = (const float*)d_in[12];
  const float* oB      = (const float*)d_in[13];
  const int*   guC     = (const int*)d_in[14];
  const float* guS     = (const float*)d_in[15];
  const float* guA     = (const float*)d_in[16];
  const float* guB     = (const float*)d_in[17];
  const int*   dnC     = (const int*)d_in[18];
  const float* dnS     = (const float*)d_in[19];
  const float* dnA     = (const float*)d_in[20];
  const float* dnB     = (const float*)d_in[21];
  float* out = (float*)d_out;

  const int M = M_TOK, Mp = M_PAD, D = D_MODEL, F = F_FFN, R = LRANK;
  float* p = (float*)d_ws;
  float* h    = p; p += (size_t)Mp * D;
  float* qkv  = p; p += (size_t)Mp * 3 * D;   // also reused as gbf (bf16) later
  float* gu   = p; p += (size_t)Mp * 2 * F;
  float* t    = p; p += (size_t)Mp * 48;
  float* cosT = p; p += SEQ * 64;
  float* sinT = p; p += SEQ * 64;
  unsigned short* xbf = (unsigned short*)p; p += (size_t)Mp * D / 2;
  unsigned short* gbf = (unsigned short*)qkv;   // Mp*F ushorts <= Mp*3*D floats

  rope_table<<<(SEQ*64 + 63)/64, 64, 0, stream>>>(cosT, sinT);
  embed_gather<<<(M * D)/256, 256, 0, stream>>>(embed, ids, h);

  const int mb = Mp / 128;

  for (int l = 0; l < NLAYER; ++l) {
    // ---- attention ----
    rmsnorm_k<<<M, 256, 0, stream>>>(h, ln_attn + (size_t)l * D, xbf, D);
    gemm_dq<<<mb * (3*D/128), 256, 0, stream>>>(
        xbf, qkvC + (size_t)l*3*D*D, qkvS + (size_t)l*3*D*(D/64), qkv,
        mb, 3*D, D, 0);
    lora1<<<dim3(M, 3), 256, 0, stream>>>(xbf, qkvA + (size_t)l*3*R*D, t, D);
    lora2<<<dim3(3*D/256, M), 256, 0, stream>>>(
        qkv, t, qkvB + (size_t)l*3*D*R, 3*D, 11, 48);
    rope_apply<<<((size_t)M*NHEAD*64 + 255)/256, 256, 0, stream>>>(qkv, cosT, sinT);
    attn_k<<<BATCH*NHEAD, 256, 0, stream>>>(qkv, amask, xbf);
    gemm_dq<<<mb * (D/128), 256, 0, stream>>>(
        xbf, oC + (size_t)l*D*D, oS + (size_t)l*D*(D/64), h, mb, D, D, 1);
    lora1<<<dim3(M, 1), 256, 0, stream>>>(xbf, oA + (size_t)l*R*D, t, D);
    lora2<<<dim3(D/256, M), 256, 0, stream>>>(h, t, oB + (size_t)l*D*R, D, 11, 16);

    // ---- MLP ----
    rmsnorm_k<<<M, 256, 0, stream>>>(h, ln_mlp + (size_t)l * D, xbf, D);
    gemm_dq<<<mb * (2*F/128), 256, 0, stream>>>(
        xbf, guC + (size_t)l*2*F*D, guS + (size_t)l*2*F*(D/64), gu,
        mb, 2*F, D, 0);
    lora1<<<dim3(M, 2), 256, 0, stream>>>(xbf, guA + (size_t)l*2*R*D, t, D);
    lora2<<<dim3(2*F/256, M), 256, 0, stream>>>(
        gu, t, guB + (size_t)l*2*F*R, 2*F, 13, 32);
    silu_mul<<<((size_t)M * F)/256, 256, 0, stream>>>(gu, gbf);
    gemm_dq<<<mb * (D/128), 256, 0, stream>>>(
        gbf, dnC + (size_t)l*D*F, dnS + (size_t)l*D*(F/64), h, mb, D, F, 1);
    lora1<<<dim3(M, 1), 256, 0, stream>>>(gbf, dnA + (size_t)l*R*F, t, F);
    lora2<<<dim3(D/256, M), 256, 0, stream>>>(h, t, dnB + (size_t)l*D*R, D, 11, 16);
  }
  final_k<<<BATCH, 256, 0, stream>>>(h, amask, ln_fin, out);
}

// Round 3
// 3009.939 us; speedup vs baseline: 1.0852x; 1.0852x over previous
//
#include <hip/hip_runtime.h>
#include <cstdint>
#include <cstddef>

#define M_TOK   1232      // B*S
#define M_PAD   1280
#define D_MODEL 2048
#define F_FFN   8192
#define SEQ     77
#define BATCH   16
#define NHEAD   16
#define LRANK   16
#define NLAYER  2

typedef short bf16x8 __attribute__((ext_vector_type(8)));
typedef float f32x4  __attribute__((ext_vector_type(4)));

__device__ __constant__ float NF4C[16] = {
  -1.0f, -0.6961928009986877f, -0.5250730514526367f, -0.39491748809814453f,
  -0.28444138169288635f, -0.18477343022823334f, -0.09105003625154495f, 0.0f,
  0.07958029955625534f, 0.16093020141124725f, 0.24611230194568634f,
  0.33791524171829224f, 0.44070982933044434f, 0.5626170039176941f,
  0.723855197429657f, 1.0f };

__device__ inline unsigned short f2b(float f) {
  unsigned u = __builtin_bit_cast(unsigned, f);
  u += 0x7FFFu + ((u >> 16) & 1u);   // RNE
  return (unsigned short)(u >> 16);
}
__device__ inline float b2f(unsigned short s) {
  return __builtin_bit_cast(float, ((unsigned)s) << 16);
}

// ---------------------------------------------------------------------------
// Fused NF4-dequant GEMM, software-pipelined.
// O[M][N] (+)= X[M][K] @ W^T;  W[n][k] = NF4[C[n][k]] * AM[n][k/64]
// BM=BN=128, BK=64 (= absmax block), 4 waves (2x2), wave does 64x64 via 4x4
// 16x16x32 bf16 MFMA. Per tile: unscaled MFMA acc, then f32 scale-accumulate.
// Pipeline: X double-buffered LDS via global_load_lds; W codes for t+2 held
// in regs; all global loads issued inside the MFMA segment so the barrier
// vmcnt(0) drain lands after a full compute phase. Split-K via f32 atomics.
// ---------------------------------------------------------------------------
__global__ __launch_bounds__(256, 2) void gemm_dq(
    const unsigned short* __restrict__ X, const int* __restrict__ C,
    const float* __restrict__ AM, float* __restrict__ O,
    int mb, int N, int K, int acc_mode, int splitk)
{
  __shared__ __align__(16) unsigned short xs[2][128 * 64];
  __shared__ __align__(16) unsigned short wsL[128 * 64];
  __shared__ unsigned int tbl[256];

  int tid = threadIdx.x;
  { int hi = tid >> 4, lo = tid & 15;
    tbl[tid] = ((unsigned)f2b(NF4C[hi]) << 16) | (unsigned)f2b(NF4C[lo]); }

  // XCD-chunked bijective swizzle
  int nwg = gridDim.x;
  int q8 = nwg >> 3, r8 = nwg & 7;
  int xcd = blockIdx.x & 7, pos = blockIdx.x >> 3;
  int wgid = (xcd < r8) ? (xcd * (q8 + 1) + pos)
                        : (r8 * (q8 + 1) + (xcd - r8) * q8 + pos);
  int nb = N >> 7;
  int per = mb * nb;
  int slice = wgid / per; int rem = wgid - slice * per;
  int nblk = rem / mb, mblk = rem - nblk * mb;
  int row0 = mblk << 7, col0 = nblk << 7;
  int KBtot = K >> 6, kcnt = KBtot / splitk, kbeg = slice * kcnt;

  int wave = tid >> 6, lane = tid & 63;
  int fr = lane & 15, fg = lane >> 4, s7 = fr & 7;
  int wm = (wave >> 1) * 64, wn = (wave & 1) * 64;
  int srow = tid >> 1, kseg = (tid & 1) * 32, n7 = srow & 7;
  int xg = lane >> 3;
  int xcol = (((lane & 7) ^ (xg & 7)) << 3);

  const unsigned short* Xbase = X + (size_t)row0 * K + (size_t)kbeg * 64;
  const int* Cbase = C + (size_t)(col0 + srow) * K + (size_t)kbeg * 64 + kseg;
  const float* amBase = AM + (size_t)(col0 + wn + fr) * KBtot + kbeg;

  f32x4 accm[4][4];
  #pragma unroll
  for (int i = 0; i < 4; ++i)
    #pragma unroll
    for (int j = 0; j < 4; ++j) accm[i][j] = (f32x4){0.f, 0.f, 0.f, 0.f};

  auto stage_x = [&](int t, int bufIdx) {
    const unsigned short* xb = Xbase + (size_t)t * 64;
    unsigned short* dst = &xs[bufIdx][0];
    #pragma unroll
    for (int p2 = 0; p2 < 4; ++p2) {
      int c = wave * 4 + p2;
      const unsigned short* gp = xb + (size_t)(c * 8 + xg) * K + xcol;
      __builtin_amdgcn_global_load_lds(
          (const __attribute__((address_space(1))) unsigned int*)gp,
          (__attribute__((address_space(3))) unsigned int*)(dst + c * 512),
          16, 0, 0);
    }
  };
  auto load_codes = [&](int t, int4* cr) {
    const int4* cp = (const int4*)(Cbase + (size_t)t * 64);
    #pragma unroll
    for (int h2 = 0; h2 < 8; ++h2) cr[h2] = cp[h2];
  };
  auto dequant = [&](const int4* cr) {
    unsigned short* wrow = wsL + srow * 64;
    #pragma unroll
    for (int h2 = 0; h2 < 4; ++h2) {
      int4 ca = cr[2 * h2], cb = cr[2 * h2 + 1];
      uint4 pk;
      pk.x = tbl[(ca.y << 4) | ca.x];
      pk.y = tbl[(ca.w << 4) | ca.z];
      pk.z = tbl[(cb.y << 4) | cb.x];
      pk.w = tbl[(cb.w << 4) | cb.z];
      int slot = (kseg >> 3) + h2;
      *(uint4*)(wrow + ((slot ^ n7) << 3)) = pk;
    }
  };
  auto compute = [&](const unsigned short* xb, const float* amv) {
    const f32x4 zq = (f32x4){0.f, 0.f, 0.f, 0.f};
    bf16x8 b0[4], b1[4];
    #pragma unroll
    for (int ni = 0; ni < 4; ++ni) {
      const unsigned short* wr = wsL + (wn + ni * 16 + fr) * 64;
      b0[ni] = *(const bf16x8*)(wr + ((fg ^ s7) << 3));
      b1[ni] = *(const bf16x8*)(wr + (((4 | fg) ^ s7) << 3));
    }
    #pragma unroll
    for (int mi = 0; mi < 4; ++mi) {
      const unsigned short* xr = xb + (wm + mi * 16 + fr) * 64;
      bf16x8 a0 = *(const bf16x8*)(xr + ((fg ^ s7) << 3));
      bf16x8 a1 = *(const bf16x8*)(xr + (((4 | fg) ^ s7) << 3));
      f32x4 t0 = __builtin_amdgcn_mfma_f32_16x16x32_bf16(a0, b0[0], zq, 0, 0, 0);
      f32x4 t1 = __builtin_amdgcn_mfma_f32_16x16x32_bf16(a0, b0[1], zq, 0, 0, 0);
      f32x4 t2 = __builtin_amdgcn_mfma_f32_16x16x32_bf16(a0, b0[2], zq, 0, 0, 0);
      f32x4 t3 = __builtin_amdgcn_mfma_f32_16x16x32_bf16(a0, b0[3], zq, 0, 0, 0);
      t0 = __builtin_amdgcn_mfma_f32_16x16x32_bf16(a1, b1[0], t0, 0, 0, 0);
      t1 = __builtin_amdgcn_mfma_f32_16x16x32_bf16(a1, b1[1], t1, 0, 0, 0);
      t2 = __builtin_amdgcn_mfma_f32_16x16x32_bf16(a1, b1[2], t2, 0, 0, 0);
      t3 = __builtin_amdgcn_mfma_f32_16x16x32_bf16(a1, b1[3], t3, 0, 0, 0);
      accm[mi][0] += amv[0] * t0;
      accm[mi][1] += amv[1] * t1;
      accm[mi][2] += amv[2] * t2;
      accm[mi][3] += amv[3] * t3;
    }
  };

  // ---- prologue ----
  int4 crA[8], crB[8];
  float amvA[4], amvB[4];
  stage_x(0, 0);
  load_codes(0, crA);
  load_codes(1, crB);          // kcnt >= 2 always
  #pragma unroll
  for (int ni = 0; ni < 4; ++ni) amvA[ni] = amBase[ni * 16 * KBtot];
  __syncthreads();             // tbl ready; prologue loads drain here

  // ---- main loop (kcnt even: 16 or 32) ----
  for (int t = 0; t < kcnt; t += 2) {
    // even phase: tile t  (crA, amvA, xs[0])
    dequant(crA);
    __syncthreads();                               // wsL = W[t]
    if (t + 1 < kcnt) stage_x(t + 1, 1);
    if (t + 2 < kcnt) load_codes(t + 2, crA);
    if (t + 1 < kcnt) {
      #pragma unroll
      for (int ni = 0; ni < 4; ++ni) amvB[ni] = amBase[ni * 16 * KBtot + t + 1];
    }
    compute(&xs[0][0], amvA);
    __syncthreads();                               // loads issued above drain here

    // odd phase: tile t+1  (crB, amvB, xs[1])
    dequant(crB);
    __syncthreads();
    if (t + 2 < kcnt) stage_x(t + 2, 0);
    if (t + 3 < kcnt) load_codes(t + 3, crB);
    if (t + 2 < kcnt) {
      #pragma unroll
      for (int ni = 0; ni < 4; ++ni) amvA[ni] = amBase[ni * 16 * KBtot + t + 2];
    }
    compute(&xs[1][0], amvB);
    __syncthreads();
  }

  // ---- epilogue ----
  #pragma unroll
  for (int mi = 0; mi < 4; ++mi)
    #pragma unroll
    for (int ni = 0; ni < 4; ++ni) {
      int gm0 = row0 + wm + mi * 16 + fg * 4;
      int gn = col0 + wn + ni * 16 + fr;
      #pragma unroll
      for (int r = 0; r < 4; ++r) {
        int gm = gm0 + r;
        if (gm < M_TOK) {
          size_t idx = (size_t)gm * N + gn;
          float vv = accm[mi][ni][r];
          if (splitk > 1)       atomicAdd(&O[idx], vv);
          else if (acc_mode)    O[idx] += vv;
          else                  O[idx] = vv;
        }
      }
    }
}

// ---------------------------------------------------------------------------
// LoRA stage 1: T[m][bi*16+g] = sum_k X[m][k] * A[bi][g][k]  (bf16 x, vec x4)
__global__ __launch_bounds__(256) void lora1(
    const unsigned short* __restrict__ X, const float* __restrict__ A,
    float* __restrict__ T, int K)
{
  int m = blockIdx.x, bi = blockIdx.y, nmat = gridDim.y;
  int g = threadIdx.x >> 4, l16 = threadIdx.x & 15;
  const unsigned short* xr = X + (size_t)m * K;
  const float* ar = A + (size_t)bi * LRANK * K + (size_t)g * K;
  float s = 0.f;
  for (int kk = l16 * 4; kk < K; kk += 64) {
    ushort4 xv = *(const ushort4*)(xr + kk);
    float4 av = *(const float4*)(ar + kk);
    s += b2f(xv.x) * av.x + b2f(xv.y) * av.y + b2f(xv.z) * av.z + b2f(xv.w) * av.w;
  }
  #pragma unroll
  for (int off = 8; off; off >>= 1) s += __shfl_down(s, off, 16);
  if (l16 == 0) T[(size_t)m * nmat * LRANK + bi * LRANK + g] = s;
}

// LoRA stage 2: O[m][n] += 2 * sum_r T[m][(n>>sh)*16+r] * Bm[n][r]
__global__ __launch_bounds__(256) void lora2(
    float* __restrict__ O, const float* __restrict__ T,
    const float* __restrict__ Bm, int N, int sh, int nr)
{
  int m = blockIdx.y;
  int n = blockIdx.x * 256 + threadIdx.x;
  __shared__ float ts[48];
  if (threadIdx.x < nr) ts[threadIdx.x] = T[(size_t)m * nr + threadIdx.x];
  __syncthreads();
  const float* tsb = ts + ((n >> sh) << 4);
  const float4* br = (const float4*)(Bm + (size_t)n * LRANK);
  float s = 0.f;
  #pragma unroll
  for (int v2 = 0; v2 < 4; ++v2) {
    float4 b = br[v2];
    s += b.x * tsb[v2*4+0] + b.y * tsb[v2*4+1] + b.z * tsb[v2*4+2] + b.w * tsb[v2*4+3];
  }
  O[(size_t)m * N + n] += 2.0f * s;
}

// ---------------------------------------------------------------------------
__global__ __launch_bounds__(256) void rmsnorm_k(
    const float* __restrict__ H, const float* __restrict__ W,
    unsigned short* __restrict__ X, int D)
{
  int m = blockIdx.x;
  const float* hr = H + (size_t)m * D;
  float s = 0.f;
  for (int i = threadIdx.x; i < D; i += 256) { float v = hr[i]; s += v * v; }
  __shared__ float red[4];
  #pragma unroll
  for (int off = 32; off; off >>= 1) s += __shfl_down(s, off, 64);
  if ((threadIdx.x & 63) == 0) red[threadIdx.x >> 6] = s;
  __syncthreads();
  float tot = red[0] + red[1] + red[2] + red[3];
  float inv = rsqrtf(tot / (float)D + 1e-6f);
  for (int i = threadIdx.x; i < D; i += 256)
    X[(size_t)m * D + i] = f2b(hr[i] * inv * W[i]);
}

__global__ void rope_table(float* __restrict__ cosT, float* __restrict__ sinT)
{
  int idx = blockIdx.x * 64 + threadIdx.x;
  if (idx >= SEQ * 64) return;
  int s = idx >> 6, j = idx & 63;
  float inv = powf(10000.0f, -(float)(2 * j) / 128.0f);
  float f = (float)s * inv;
  cosT[idx] = cosf(f);
  sinT[idx] = sinf(f);
}

// QKV packed buffer: row stride 6144; q at +0, k at +2048
__global__ void rope_apply(float* __restrict__ QKV,
                           const float* __restrict__ cosT, const float* __restrict__ sinT)
{
  size_t idx = (size_t)blockIdx.x * 256 + threadIdx.x;
  if (idx >= (size_t)M_TOK * NHEAD * 64) return;
  int j = (int)(idx & 63);
  int h = (int)((idx >> 6) & (NHEAD - 1));
  int m = (int)(idx >> 10);
  int s = m % SEQ;
  float c = cosT[s * 64 + j], sn = sinT[s * 64 + j];
  size_t base = (size_t)m * (3 * D_MODEL) + h * 128;
  float q1 = QKV[base + j], q2 = QKV[base + 64 + j];
  QKV[base + j]      = q1 * c - q2 * sn;
  QKV[base + 64 + j] = q2 * c + q1 * sn;
  size_t kb = base + D_MODEL;
  float k1 = QKV[kb + j], k2 = QKV[kb + 64 + j];
  QKV[kb + j]      = k1 * c - k2 * sn;
  QKV[kb + 64 + j] = k2 * c + k1 * sn;
}

__global__ __launch_bounds__(256) void attn_k(
    const float* __restrict__ QKV, const int* __restrict__ amask,
    unsigned short* __restrict__ O)
{
  int bh = blockIdx.x;
  int b = bh / NHEAD, h = bh % NHEAD;
  __shared__ float sc[SEQ * SEQ];
  const float scale = 0.08838834764831845f;  // 1/sqrt(128)
  const int STR = 3 * D_MODEL;
  for (int idx = threadIdx.x; idx < SEQ * SEQ; idx += 256) {
    int i = idx / SEQ, j = idx % SEQ;
    float val = -1e9f;
    if (j <= i && amask[b * SEQ + j] != 0) {
      const float4* qr = (const float4*)(QKV + (size_t)(b*SEQ+i) * STR + h*128);
      const float4* kr = (const float4*)(QKV + (size_t)(b*SEQ+j) * STR + D_MODEL + h*128);
      float s = 0.f;
      #pragma unroll 8
      for (int d = 0; d < 32; ++d) {
        float4 a = qr[d], c = kr[d];
        s += a.x*c.x + a.y*c.y + a.z*c.z + a.w*c.w;
      }
      val = s * scale;
    }
    sc[idx] = val;
  }
  __syncthreads();
  for (int i = threadIdx.x; i < SEQ; i += 256) {
    float mx = -1e30f;
    for (int j = 0; j < SEQ; ++j) mx = fmaxf(mx, sc[i*SEQ+j]);
    float sum = 0.f;
    for (int j = 0; j < SEQ; ++j) { float e = expf(sc[i*SEQ+j] - mx); sc[i*SEQ+j] = e; sum += e; }
    float inv = 1.0f / sum;
    for (int j = 0; j < SEQ; ++j) sc[i*SEQ+j] *= inv;
  }
  __syncthreads();
  for (int idx = threadIdx.x; idx < SEQ * 128; idx += 256) {
    int i = idx >> 7, d = idx & 127;
    float s = 0.f;
    for (int j = 0; j < SEQ; ++j)
      s += sc[i*SEQ+j] * QKV[(size_t)(b*SEQ+j) * STR + 2*D_MODEL + h*128 + d];
    O[(size_t)(b*SEQ+i) * D_MODEL + h*128 + d] = f2b(s);
  }
}

__global__ void embed_gather(const float* __restrict__ E, const int* __restrict__ ids,
                             float* __restrict__ H)
{
  size_t idx = (size_t)blockIdx.x * 256 + threadIdx.x;
  int m = (int)(idx / D_MODEL);
  int n = (int)(idx % D_MODEL);
  H[idx] = E[(size_t)ids[m] * D_MODEL + n];
}

// GU packed buffer: row stride 16384; g at +0, up at +8192. Output bf16.
__global__ void silu_mul(const float* __restrict__ GU, unsigned short* __restrict__ GB)
{
  size_t id = (size_t)blockIdx.x * 256 + threadIdx.x;
  int m = (int)(id >> 13), n = (int)(id & (F_FFN - 1));
  float g = GU[(size_t)m * 2 * F_FFN + n];
  float u = GU[(size_t)m * 2 * F_FFN + F_FFN + n];
  float sig = 1.0f / (1.0f + expf(-g));
  GB[id] = f2b(g * sig * u);
}

__global__ __launch_bounds__(256) void final_k(
    const float* __restrict__ H, const int* __restrict__ amask,
    const float* __restrict__ W, float* __restrict__ out)
{
  int b = blockIdx.x;
  __shared__ int len;
  if (threadIdx.x == 0) {
    int s = 0;
    for (int j = 0; j < SEQ; ++j) s += amask[b * SEQ + j];
    len = s - 1;
  }
  __syncthreads();
  const float* hr = H + ((size_t)(b * SEQ + len) * D_MODEL);
  float s = 0.f;
  for (int i = threadIdx.x; i < D_MODEL; i += 256) { float v = hr[i]; s += v * v; }
  __shared__ float red[4];
  #pragma unroll
  for (int off = 32; off; off >>= 1) s += __shfl_down(s, off, 64);
  if ((threadIdx.x & 63) == 0) red[threadIdx.x >> 6] = s;
  __syncthreads();
  float tot = red[0] + red[1] + red[2] + red[3];
  float inv = rsqrtf(tot / (float)D_MODEL + 1e-6f);
  for (int i = threadIdx.x; i < D_MODEL; i += 256)
    out[(size_t)b * D_MODEL + i] = hr[i] * inv * W[i];
}

// ---------------------------------------------------------------------------
extern "C" void kernel_launch(void* const* d_in, const int* in_sizes, int n_in,
                              void* d_out, int out_size, void* d_ws, size_t ws_size,
                              hipStream_t stream) {
  const int*   ids     = (const int*)d_in[0];
  const int*   amask   = (const int*)d_in[1];
  const float* embed   = (const float*)d_in[2];
  const float* ln_attn = (const float*)d_in[3];
  const float* ln_mlp  = (const float*)d_in[4];
  const float* ln_fin  = (const float*)d_in[5];
  const int*   qkvC    = (const int*)d_in[6];
  const float* qkvS    = (const float*)d_in[7];
  const float* qkvA    = (const float*)d_in[8];
  const float* qkvB    = (const float*)d_in[9];
  const int*   oC      = (const int*)d_in[10];
  const float* oS      = (const float*)d_in[11];
  const float* oA      = (const float*)d_in[12];
  const float* oB      = (const float*)d_in[13];
  const int*   guC     = (const int*)d_in[14];
  const float* guS     = (const float*)d_in[15];
  const float* guA     = (const float*)d_in[16];
  const float* guB     = (const float*)d_in[17];
  const int*   dnC     = (const int*)d_in[18];
  const float* dnS     = (const float*)d_in[19];
  const float* dnA     = (const float*)d_in[20];
  const float* dnB     = (const float*)d_in[21];
  float* out = (float*)d_out;

  const int M = M_TOK, Mp = M_PAD, D = D_MODEL, F = F_FFN, R = LRANK;
  float* p = (float*)d_ws;
  float* h    = p; p += (size_t)Mp * D;
  float* qkv  = p; p += (size_t)Mp * 3 * D;   // also reused as gbf (bf16) later
  float* gu   = p; p += (size_t)Mp * 2 * F;
  float* t    = p; p += (size_t)Mp * 48;
  float* cosT = p; p += SEQ * 64;
  float* sinT = p; p += SEQ * 64;
  unsigned short* xbf = (unsigned short*)p; p += (size_t)Mp * D / 2;
  unsigned short* gbf = (unsigned short*)qkv;   // Mp*F ushorts <= Mp*3*D floats

  rope_table<<<(SEQ*64 + 63)/64, 64, 0, stream>>>(cosT, sinT);
  embed_gather<<<(M * D)/256, 256, 0, stream>>>(embed, ids, h);

  const int mb = Mp / 128;

  for (int l = 0; l < NLAYER; ++l) {
    // ---- attention ----
    rmsnorm_k<<<M, 256, 0, stream>>>(h, ln_attn + (size_t)l * D, xbf, D);
    gemm_dq<<<mb * (3*D/128), 256, 0, stream>>>(
        xbf, qkvC + (size_t)l*3*D*D, qkvS + (size_t)l*3*D*(D/64), qkv,
        mb, 3*D, D, 0, 1);
    lora1<<<dim3(M, 3), 256, 0, stream>>>(xbf, qkvA + (size_t)l*3*R*D, t, D);
    lora2<<<dim3(3*D/256, M), 256, 0, stream>>>(
        qkv, t, qkvB + (size_t)l*3*D*R, 3*D, 11, 48);
    rope_apply<<<((size_t)M*NHEAD*64 + 255)/256, 256, 0, stream>>>(qkv, cosT, sinT);
    attn_k<<<BATCH*NHEAD, 256, 0, stream>>>(qkv, amask, xbf);
    gemm_dq<<<mb * (D/128) * 2, 256, 0, stream>>>(
        xbf, oC + (size_t)l*D*D, oS + (size_t)l*D*(D/64), h, mb, D, D, 1, 2);
    lora1<<<dim3(M, 1), 256, 0, stream>>>(xbf, oA + (size_t)l*R*D, t, D);
    lora2<<<dim3(D/256, M), 256, 0, stream>>>(h, t, oB + (size_t)l*D*R, D, 11, 16);

    // ---- MLP ----
    rmsnorm_k<<<M, 256, 0, stream>>>(h, ln_mlp + (size_t)l * D, xbf, D);
    gemm_dq<<<mb * (2*F/128), 256, 0, stream>>>(
        xbf, guC + (size_t)l*2*F*D, guS + (size_t)l*2*F*(D/64), gu,
        mb, 2*F, D, 0, 1);
    lora1<<<dim3(M, 2), 256, 0, stream>>>(xbf, guA + (size_t)l*2*R*D, t, D);
    lora2<<<dim3(2*F/256, M), 256, 0, stream>>>(
        gu, t, guB + (size_t)l*2*F*R, 2*F, 13, 32);
    silu_mul<<<((size_t)M * F)/256, 256, 0, stream>>>(gu, gbf);
    gemm_dq<<<mb * (D/128) * 4, 256, 0, stream>>>(
        gbf, dnC + (size_t)l*D*F, dnS + (size_t)l*D*(F/64), h, mb, D, F, 1, 4);
    lora1<<<dim3(M, 1), 256, 0, stream>>>(gbf, dnA + (size_t)l*R*F, t, F);
    lora2<<<dim3(D/256, M), 256, 0, stream>>>(h, t, dnB + (size_t)l*D*R, D, 11, 16);
  }
  final_k<<<BATCH, 256, 0, stream>>>(h, amask, ln_fin, out);
}

// Round 4
// 2288.220 us; speedup vs baseline: 1.4274x; 1.3154x over previous
//
#include <hip/hip_runtime.h>
#include <cstdint>
#include <cstddef>

#define M_TOK   1232      // B*S
#define M_PAD   1280
#define D_MODEL 2048
#define F_FFN   8192
#define SEQ     77
#define BATCH   16
#define NHEAD   16
#define LRANK   16
#define NLAYER  2

typedef short bf16x8 __attribute__((ext_vector_type(8)));
typedef float f32x4  __attribute__((ext_vector_type(4)));

__device__ __constant__ float NF4C[16] = {
  -1.0f, -0.6961928009986877f, -0.5250730514526367f, -0.39491748809814453f,
  -0.28444138169288635f, -0.18477343022823334f, -0.09105003625154495f, 0.0f,
  0.07958029955625534f, 0.16093020141124725f, 0.24611230194568634f,
  0.33791524171829224f, 0.44070982933044434f, 0.5626170039176941f,
  0.723855197429657f, 1.0f };

__device__ inline unsigned short f2b(float f) {
  unsigned u = __builtin_bit_cast(unsigned, f);
  u += 0x7FFFu + ((u >> 16) & 1u);   // RNE
  return (unsigned short)(u >> 16);
}
__device__ inline float b2f(unsigned short s) {
  return __builtin_bit_cast(float, ((unsigned)s) << 16);
}

// ---------------------------------------------------------------------------
// Pack int32 NF4 codes -> nibble bytes, tile-major layout matching the GEMM:
// tile (nblk,kt) = 1024 u32; within tile u32 w: tid2=w>>2, word=w&3,
// srow=tid2>>1, kseg=(tid2&1)*32, n=nblk*128+srow, k0=kt*64+kseg+word*8.
// ---------------------------------------------------------------------------
__global__ void pack_codes(const int* __restrict__ C, unsigned* __restrict__ P,
                           int K, int kbshift, int total)
{
  for (int o = blockIdx.x * 256 + threadIdx.x; o < total; o += gridDim.x * 256) {
    int tile = o >> 10, w = o & 1023;
    int kt = tile & ((1 << kbshift) - 1), nblk = tile >> kbshift;
    int tid2 = w >> 2, word = w & 3;
    int srow = tid2 >> 1, kseg = (tid2 & 1) << 5;
    const int* cp = C + ((size_t)((nblk << 7) + srow)) * K + (kt << 6) + kseg + (word << 3);
    int4 a = *(const int4*)cp;
    int4 b = *(const int4*)(cp + 4);
    P[o] = (unsigned)a.x | ((unsigned)a.y << 4) | ((unsigned)a.z << 8) | ((unsigned)a.w << 12)
         | ((unsigned)b.x << 16) | ((unsigned)b.y << 20) | ((unsigned)b.z << 24)
         | ((unsigned)b.w << 28);
  }
}

// ---------------------------------------------------------------------------
// Fused NF4-dequant GEMM on packed codes. BM=BN=128, BK=64 (=absmax block),
// 4 waves 2x2, wave = 64x64 via 4x4 16x16x32 bf16 MFMA. One barrier per tile:
// segment = [stage X(t+1) via global_load_lds | dequant codes(t+1)->other LDS
// half | compute(t) | reload code regs] -> __syncthreads().
// ---------------------------------------------------------------------------
__global__ __launch_bounds__(256, 2) void gemm_dq(
    const unsigned short* __restrict__ X, const unsigned* __restrict__ Cpk,
    const float* __restrict__ AM, float* __restrict__ O,
    int mb, int N, int K, int acc_mode, int splitk)
{
  __shared__ __align__(16) unsigned short xs[2][128 * 64];
  __shared__ __align__(16) unsigned short wsL[2][128 * 64];
  __shared__ unsigned int tbl[256];

  int tid = threadIdx.x;
  { int hi = tid >> 4, lo = tid & 15;
    tbl[tid] = ((unsigned)f2b(NF4C[hi]) << 16) | (unsigned)f2b(NF4C[lo]); }

  // XCD-chunked bijective swizzle
  int nwg = gridDim.x;
  int q8 = nwg >> 3, r8 = nwg & 7;
  int xcd = blockIdx.x & 7, pos = blockIdx.x >> 3;
  int wgid = (xcd < r8) ? (xcd * (q8 + 1) + pos)
                        : (r8 * (q8 + 1) + (xcd - r8) * q8 + pos);
  int nb = N >> 7;
  int per = mb * nb;
  int slice = wgid / per; int rem = wgid - slice * per;
  int nblk = rem / mb, mblk = rem - nblk * mb;
  int row0 = mblk << 7, col0 = nblk << 7;
  int KBtot = K >> 6, kcnt = KBtot / splitk, kbeg = slice * kcnt;

  int wave = tid >> 6, lane = tid & 63;
  int fr = lane & 15, fg = lane >> 4, s7 = fr & 7;
  int wm = (wave >> 1) * 64, wn = (wave & 1) * 64;
  int srow = tid >> 1, kseg = (tid & 1) * 32, n7 = srow & 7;
  int xg = lane >> 3;
  int xcol = (((lane & 7) ^ (xg & 7)) << 3);

  const unsigned short* Xbase = X + (size_t)row0 * K + (size_t)kbeg * 64;
  const uint4* Cp4 = (const uint4*)(Cpk + (((size_t)nblk * KBtot) << 10)) + tid;
  const float* amBase = AM + (size_t)(col0 + wn + fr) * KBtot + kbeg;

  f32x4 accm[4][4];
  #pragma unroll
  for (int i = 0; i < 4; ++i)
    #pragma unroll
    for (int j = 0; j < 4; ++j) accm[i][j] = (f32x4){0.f, 0.f, 0.f, 0.f};

  auto stage_x = [&](int t, int bufIdx) {
    const unsigned short* xb = Xbase + (size_t)t * 64;
    unsigned short* dst = &xs[bufIdx][0];
    #pragma unroll
    for (int p2 = 0; p2 < 4; ++p2) {
      int c = wave * 4 + p2;
      const unsigned short* gp = xb + (size_t)(c * 8 + xg) * K + xcol;
      __builtin_amdgcn_global_load_lds(
          (const __attribute__((address_space(1))) unsigned int*)gp,
          (__attribute__((address_space(3))) unsigned int*)(dst + c * 512),
          16, 0, 0);
    }
  };
  auto cpk_load = [&](int t) -> uint4 {
    return Cp4[(size_t)(kbeg + t) << 8];
  };
  auto dequant = [&](uint4 cw, unsigned short* wbuf) {
    unsigned short* wrow = wbuf + srow * 64;
    #pragma unroll
    for (int j = 0; j < 4; ++j) {
      unsigned w = (j == 0) ? cw.x : (j == 1) ? cw.y : (j == 2) ? cw.z : cw.w;
      uint4 pk;
      pk.x = tbl[w & 255];
      pk.y = tbl[(w >> 8) & 255];
      pk.z = tbl[(w >> 16) & 255];
      pk.w = tbl[w >> 24];
      int slot = (kseg >> 3) + j;
      *(uint4*)(wrow + ((slot ^ n7) << 3)) = pk;
    }
  };
  auto compute = [&](const unsigned short* xb, const unsigned short* wb,
                     const float* amv) {
    const f32x4 zq = (f32x4){0.f, 0.f, 0.f, 0.f};
    bf16x8 b0[4], b1[4];
    #pragma unroll
    for (int ni = 0; ni < 4; ++ni) {
      const unsigned short* wr = wb + (wn + ni * 16 + fr) * 64;
      b0[ni] = *(const bf16x8*)(wr + ((fg ^ s7) << 3));
      b1[ni] = *(const bf16x8*)(wr + (((4 | fg) ^ s7) << 3));
    }
    #pragma unroll
    for (int mi = 0; mi < 4; ++mi) {
      const unsigned short* xr = xb + (wm + mi * 16 + fr) * 64;
      bf16x8 a0 = *(const bf16x8*)(xr + ((fg ^ s7) << 3));
      bf16x8 a1 = *(const bf16x8*)(xr + (((4 | fg) ^ s7) << 3));
      f32x4 t0 = __builtin_amdgcn_mfma_f32_16x16x32_bf16(a0, b0[0], zq, 0, 0, 0);
      f32x4 t1 = __builtin_amdgcn_mfma_f32_16x16x32_bf16(a0, b0[1], zq, 0, 0, 0);
      f32x4 t2 = __builtin_amdgcn_mfma_f32_16x16x32_bf16(a0, b0[2], zq, 0, 0, 0);
      f32x4 t3 = __builtin_amdgcn_mfma_f32_16x16x32_bf16(a0, b0[3], zq, 0, 0, 0);
      t0 = __builtin_amdgcn_mfma_f32_16x16x32_bf16(a1, b1[0], t0, 0, 0, 0);
      t1 = __builtin_amdgcn_mfma_f32_16x16x32_bf16(a1, b1[1], t1, 0, 0, 0);
      t2 = __builtin_amdgcn_mfma_f32_16x16x32_bf16(a1, b1[2], t2, 0, 0, 0);
      t3 = __builtin_amdgcn_mfma_f32_16x16x32_bf16(a1, b1[3], t3, 0, 0, 0);
      accm[mi][0] += amv[0] * t0;
      accm[mi][1] += amv[1] * t1;
      accm[mi][2] += amv[2] * t2;
      accm[mi][3] += amv[3] * t3;
    }
  };

  // ---- prologue ----
  uint4 cwP, cw1, cw0;
  float amv0[4], amv1[4];
  stage_x(0, 0);
  cwP = cpk_load(0);
  cw1 = cpk_load(1);           // consumed segment 0
  cw0 = cpk_load(2);           // consumed segment 1
  #pragma unroll
  for (int ni = 0; ni < 4; ++ni) amv0[ni] = amBase[ni * 16 * KBtot];
  __syncthreads();             // tbl + X[0] + code regs ready

  stage_x(1, 1);
  dequant(cwP, &wsL[0][0]);
  #pragma unroll
  for (int ni = 0; ni < 4; ++ni) amv1[ni] = amBase[ni * 16 * KBtot + 1];
  __syncthreads();             // X[1], W[0] ready

  // ---- main loop: kcnt even (8 or 32) ----
  for (int t = 0; t < kcnt; t += 2) {
    // even segment: compute tile t from xs[0], wsL[0]
    if (t + 1 < kcnt) { stage_x(t + 1, 1); dequant(cw1, &wsL[1][0]); }
    if (t + 3 < kcnt) cw1 = cpk_load(t + 3);
    compute(&xs[0][0], &wsL[0][0], amv0);
    if (t + 2 < kcnt) {
      #pragma unroll
      for (int ni = 0; ni < 4; ++ni) amv0[ni] = amBase[ni * 16 * KBtot + t + 2];
    }
    __syncthreads();

    // odd segment: compute tile t+1 from xs[1], wsL[1]
    if (t + 2 < kcnt) { stage_x(t + 2, 0); dequant(cw0, &wsL[0][0]); }
    if (t + 4 < kcnt) cw0 = cpk_load(t + 4);
    compute(&xs[1][0], &wsL[1][0], amv1);
    if (t + 3 < kcnt) {
      #pragma unroll
      for (int ni = 0; ni < 4; ++ni) amv1[ni] = amBase[ni * 16 * KBtot + t + 3];
    }
    __syncthreads();
  }

  // ---- epilogue ----
  #pragma unroll
  for (int mi = 0; mi < 4; ++mi)
    #pragma unroll
    for (int ni = 0; ni < 4; ++ni) {
      int gm0 = row0 + wm + mi * 16 + fg * 4;
      int gn = col0 + wn + ni * 16 + fr;
      #pragma unroll
      for (int r = 0; r < 4; ++r) {
        int gm = gm0 + r;
        if (gm < M_TOK) {
          size_t idx = (size_t)gm * N + gn;
          float vv = accm[mi][ni][r];
          if (splitk > 1)       atomicAdd(&O[idx], vv);
          else if (acc_mode)    O[idx] += vv;
          else                  O[idx] = vv;
        }
      }
    }
}

// ---------------------------------------------------------------------------
// LoRA stage 1, 4 m-rows per block: T[m][bi*16+g] = sum_k X[m][k]*A[bi][g][k]
__global__ __launch_bounds__(256) void lora1(
    const unsigned short* __restrict__ X, const float* __restrict__ A,
    float* __restrict__ T, int K)
{
  int m0 = blockIdx.x * 4, bi = blockIdx.y, nmat = gridDim.y;
  int g = threadIdx.x >> 4, l16 = threadIdx.x & 15;
  const float* ar = A + (size_t)bi * LRANK * K + (size_t)g * K;
  const unsigned short* x0 = X + (size_t)m0 * K;
  float s0 = 0.f, s1 = 0.f, s2 = 0.f, s3 = 0.f;
  for (int kk = l16 * 4; kk < K; kk += 64) {
    float4 av = *(const float4*)(ar + kk);
    ushort4 v0 = *(const ushort4*)(x0 + kk);
    ushort4 v1 = *(const ushort4*)(x0 + K + kk);
    ushort4 v2 = *(const ushort4*)(x0 + 2 * K + kk);
    ushort4 v3 = *(const ushort4*)(x0 + 3 * K + kk);
    s0 += b2f(v0.x)*av.x + b2f(v0.y)*av.y + b2f(v0.z)*av.z + b2f(v0.w)*av.w;
    s1 += b2f(v1.x)*av.x + b2f(v1.y)*av.y + b2f(v1.z)*av.z + b2f(v1.w)*av.w;
    s2 += b2f(v2.x)*av.x + b2f(v2.y)*av.y + b2f(v2.z)*av.z + b2f(v2.w)*av.w;
    s3 += b2f(v3.x)*av.x + b2f(v3.y)*av.y + b2f(v3.z)*av.z + b2f(v3.w)*av.w;
  }
  #pragma unroll
  for (int off = 8; off; off >>= 1) {
    s0 += __shfl_down(s0, off, 16);
    s1 += __shfl_down(s1, off, 16);
    s2 += __shfl_down(s2, off, 16);
    s3 += __shfl_down(s3, off, 16);
  }
  if (l16 == 0) {
    size_t base = ((size_t)m0 * nmat + bi) * LRANK + g;
    size_t rs = (size_t)nmat * LRANK;
    T[base] = s0; T[base + rs] = s1; T[base + 2*rs] = s2; T[base + 3*rs] = s3;
  }
}

// LoRA stage 2, 8 m-rows per block: O[m][n] += 2*sum_r T[m][(n>>sh)*16+r]*Bm[n][r]
__global__ __launch_bounds__(256) void lora2(
    float* __restrict__ O, const float* __restrict__ T,
    const float* __restrict__ Bm, int N, int sh, int nr)
{
  int m0 = blockIdx.y * 8;
  int n = blockIdx.x * 256 + threadIdx.x;
  __shared__ float ts[8 * 48];
  for (int i = threadIdx.x; i < 8 * nr; i += 256)
    ts[(i / nr) * 48 + (i % nr)] = T[(size_t)(m0 + i / nr) * nr + (i % nr)];
  __syncthreads();
  const float4* br = (const float4*)(Bm + (size_t)n * LRANK);
  float4 b0 = br[0], b1 = br[1], b2 = br[2], b3 = br[3];
  int toff = ((n >> sh) << 4);
  #pragma unroll
  for (int mi = 0; mi < 8; ++mi) {
    const float* tsb = ts + mi * 48 + toff;
    float s = b0.x*tsb[0] + b0.y*tsb[1] + b0.z*tsb[2] + b0.w*tsb[3]
            + b1.x*tsb[4] + b1.y*tsb[5] + b1.z*tsb[6] + b1.w*tsb[7]
            + b2.x*tsb[8] + b2.y*tsb[9] + b2.z*tsb[10] + b2.w*tsb[11]
            + b3.x*tsb[12] + b3.y*tsb[13] + b3.z*tsb[14] + b3.w*tsb[15];
    O[(size_t)(m0 + mi) * N + n] += 2.0f * s;
  }
}

// ---------------------------------------------------------------------------
__global__ __launch_bounds__(256) void rmsnorm_k(
    const float* __restrict__ H, const float* __restrict__ W,
    unsigned short* __restrict__ X, int D)
{
  int m = blockIdx.x;
  const float* hr = H + (size_t)m * D;
  float s = 0.f;
  for (int i = threadIdx.x; i < D; i += 256) { float v = hr[i]; s += v * v; }
  __shared__ float red[4];
  #pragma unroll
  for (int off = 32; off; off >>= 1) s += __shfl_down(s, off, 64);
  if ((threadIdx.x & 63) == 0) red[threadIdx.x >> 6] = s;
  __syncthreads();
  float tot = red[0] + red[1] + red[2] + red[3];
  float inv = rsqrtf(tot / (float)D + 1e-6f);
  for (int i = threadIdx.x; i < D; i += 256)
    X[(size_t)m * D + i] = f2b(hr[i] * inv * W[i]);
}

__global__ void rope_table(float* __restrict__ cosT, float* __restrict__ sinT)
{
  int idx = blockIdx.x * 64 + threadIdx.x;
  if (idx >= SEQ * 64) return;
  int s = idx >> 6, j = idx & 63;
  float inv = powf(10000.0f, -(float)(2 * j) / 128.0f);
  float f = (float)s * inv;
  cosT[idx] = cosf(f);
  sinT[idx] = sinf(f);
}

// QKV packed buffer: row stride 6144; q at +0, k at +2048
__global__ void rope_apply(float* __restrict__ QKV,
                           const float* __restrict__ cosT, const float* __restrict__ sinT)
{
  size_t idx = (size_t)blockIdx.x * 256 + threadIdx.x;
  if (idx >= (size_t)M_TOK * NHEAD * 64) return;
  int j = (int)(idx & 63);
  int h = (int)((idx >> 6) & (NHEAD - 1));
  int m = (int)(idx >> 10);
  int s = m % SEQ;
  float c = cosT[s * 64 + j], sn = sinT[s * 64 + j];
  size_t base = (size_t)m * (3 * D_MODEL) + h * 128;
  float q1 = QKV[base + j], q2 = QKV[base + 64 + j];
  QKV[base + j]      = q1 * c - q2 * sn;
  QKV[base + 64 + j] = q2 * c + q1 * sn;
  size_t kb = base + D_MODEL;
  float k1 = QKV[kb + j], k2 = QKV[kb + 64 + j];
  QKV[kb + j]      = k1 * c - k2 * sn;
  QKV[kb + 64 + j] = k2 * c + k1 * sn;
}

__global__ __launch_bounds__(256) void attn_k(
    const float* __restrict__ QKV, const int* __restrict__ amask,
    unsigned short* __restrict__ O)
{
  int bh = blockIdx.x;
  int b = bh / NHEAD, h = bh % NHEAD;
  __shared__ float sc[SEQ * SEQ];
  const float scale = 0.08838834764831845f;  // 1/sqrt(128)
  const int STR = 3 * D_MODEL;
  for (int idx = threadIdx.x; idx < SEQ * SEQ; idx += 256) {
    int i = idx / SEQ, j = idx % SEQ;
    float val = -1e9f;
    if (j <= i && amask[b * SEQ + j] != 0) {
      const float4* qr = (const float4*)(QKV + (size_t)(b*SEQ+i) * STR + h*128);
      const float4* kr = (const float4*)(QKV + (size_t)(b*SEQ+j) * STR + D_MODEL + h*128);
      float s = 0.f;
      #pragma unroll 8
      for (int d = 0; d < 32; ++d) {
        float4 a = qr[d], c = kr[d];
        s += a.x*c.x + a.y*c.y + a.z*c.z + a.w*c.w;
      }
      val = s * scale;
    }
    sc[idx] = val;
  }
  __syncthreads();
  for (int i = threadIdx.x; i < SEQ; i += 256) {
    float mx = -1e30f;
    for (int j = 0; j < SEQ; ++j) mx = fmaxf(mx, sc[i*SEQ+j]);
    float sum = 0.f;
    for (int j = 0; j < SEQ; ++j) { float e = expf(sc[i*SEQ+j] - mx); sc[i*SEQ+j] = e; sum += e; }
    float inv = 1.0f / sum;
    for (int j = 0; j < SEQ; ++j) sc[i*SEQ+j] *= inv;
  }
  __syncthreads();
  // PV: float4-vectorized over d
  for (int idx = threadIdx.x; idx < SEQ * 32; idx += 256) {
    int i = idx >> 5, d4 = (idx & 31) << 2;
    float4 acc = {0.f, 0.f, 0.f, 0.f};
    for (int j = 0; j < SEQ; ++j) {
      float p = sc[i * SEQ + j];
      float4 v = *(const float4*)(QKV + (size_t)(b*SEQ+j) * STR + 2*D_MODEL + h*128 + d4);
      acc.x += p * v.x; acc.y += p * v.y; acc.z += p * v.z; acc.w += p * v.w;
    }
    unsigned short* op = O + (size_t)(b*SEQ+i) * D_MODEL + h*128 + d4;
    op[0] = f2b(acc.x); op[1] = f2b(acc.y); op[2] = f2b(acc.z); op[3] = f2b(acc.w);
  }
}

__global__ void embed_gather(const float* __restrict__ E, const int* __restrict__ ids,
                             float* __restrict__ H)
{
  size_t idx = (size_t)blockIdx.x * 256 + threadIdx.x;
  int m = (int)(idx / D_MODEL);
  int n = (int)(idx % D_MODEL);
  H[idx] = E[(size_t)ids[m] * D_MODEL + n];
}

// GU packed buffer: row stride 16384; g at +0, up at +8192. Output bf16.
__global__ void silu_mul(const float* __restrict__ GU, unsigned short* __restrict__ GB)
{
  size_t id = (size_t)blockIdx.x * 256 + threadIdx.x;
  int m = (int)(id >> 13), n = (int)(id & (F_FFN - 1));
  float g = GU[(size_t)m * 2 * F_FFN + n];
  float u = GU[(size_t)m * 2 * F_FFN + F_FFN + n];
  float sig = 1.0f / (1.0f + expf(-g));
  GB[id] = f2b(g * sig * u);
}

__global__ __launch_bounds__(256) void final_k(
    const float* __restrict__ H, const int* __restrict__ amask,
    const float* __restrict__ W, float* __restrict__ out)
{
  int b = blockIdx.x;
  __shared__ int len;
  if (threadIdx.x == 0) {
    int s = 0;
    for (int j = 0; j < SEQ; ++j) s += amask[b * SEQ + j];
    len = s - 1;
  }
  __syncthreads();
  const float* hr = H + ((size_t)(b * SEQ + len) * D_MODEL);
  float s = 0.f;
  for (int i = threadIdx.x; i < D_MODEL; i += 256) { float v = hr[i]; s += v * v; }
  __shared__ float red[4];
  #pragma unroll
  for (int off = 32; off; off >>= 1) s += __shfl_down(s, off, 64);
  if ((threadIdx.x & 63) == 0) red[threadIdx.x >> 6] = s;
  __syncthreads();
  float tot = red[0] + red[1] + red[2] + red[3];
  float inv = rsqrtf(tot / (float)D_MODEL + 1e-6f);
  for (int i = threadIdx.x; i < D_MODEL; i += 256)
    out[(size_t)b * D_MODEL + i] = hr[i] * inv * W[i];
}

// ---------------------------------------------------------------------------
extern "C" void kernel_launch(void* const* d_in, const int* in_sizes, int n_in,
                              void* d_out, int out_size, void* d_ws, size_t ws_size,
                              hipStream_t stream) {
  const int*   ids     = (const int*)d_in[0];
  const int*   amask   = (const int*)d_in[1];
  const float* embed   = (const float*)d_in[2];
  const float* ln_attn = (const float*)d_in[3];
  const float* ln_mlp  = (const float*)d_in[4];
  const float* ln_fin  = (const float*)d_in[5];
  const int*   qkvC    = (const int*)d_in[6];
  const float* qkvS    = (const float*)d_in[7];
  const float* qkvA    = (const float*)d_in[8];
  const float* qkvB    = (const float*)d_in[9];
  const int*   oC      = (const int*)d_in[10];
  const float* oS      = (const float*)d_in[11];
  const float* oA      = (const float*)d_in[12];
  const float* oB      = (const float*)d_in[13];
  const int*   guC     = (const int*)d_in[14];
  const float* guS     = (const float*)d_in[15];
  const float* guA     = (const float*)d_in[16];
  const float* guB     = (const float*)d_in[17];
  const int*   dnC     = (const int*)d_in[18];
  const float* dnS     = (const float*)d_in[19];
  const float* dnA     = (const float*)d_in[20];
  const float* dnB     = (const float*)d_in[21];
  float* out = (float*)d_out;

  const int M = M_TOK, Mp = M_PAD, D = D_MODEL, F = F_FFN, R = LRANK;
  float* p = (float*)d_ws;
  float* h    = p; p += (size_t)Mp * D;
  float* qkv  = p; p += (size_t)Mp * 3 * D;   // also reused as gbf (bf16) later
  float* gu   = p; p += (size_t)Mp * 2 * F;
  float* t    = p; p += (size_t)Mp * 48;
  float* cosT = p; p += SEQ * 64;
  float* sinT = p; p += SEQ * 64;
  unsigned short* xbf = (unsigned short*)p; p += (size_t)Mp * D / 2;
  unsigned short* gbf = (unsigned short*)qkv;   // Mp*F ushorts <= Mp*3*D floats
  // packed codes (u32 units)
  unsigned* pkQ = (unsigned*)p;                        // 2 * 3DD/8 u32
  unsigned* pkO = pkQ + (size_t)NLAYER * 3*D*D/8;
  unsigned* pkG = pkO + (size_t)NLAYER * D*D/8;
  unsigned* pkD = pkG + (size_t)NLAYER * 2*F*D/8;

  // ---- pack all weight codes (tile-major nibble layout) ----
  for (int l = 0; l < NLAYER; ++l) {
    int tq = 3*D*D/8, to = D*D/8, tg = 2*F*D/8, td = D*F/8;
    pack_codes<<<2048, 256, 0, stream>>>(qkvC + (size_t)l*3*D*D, pkQ + (size_t)l*tq, D, 5, tq);
    pack_codes<<<2048, 256, 0, stream>>>(oC   + (size_t)l*D*D,   pkO + (size_t)l*to, D, 5, to);
    pack_codes<<<2048, 256, 0, stream>>>(guC  + (size_t)l*2*F*D, pkG + (size_t)l*tg, D, 5, tg);
    pack_codes<<<2048, 256, 0, stream>>>(dnC  + (size_t)l*D*F,   pkD + (size_t)l*td, F, 7, td);
  }

  rope_table<<<(SEQ*64 + 63)/64, 64, 0, stream>>>(cosT, sinT);
  embed_gather<<<(M * D)/256, 256, 0, stream>>>(embed, ids, h);

  const int mb = Mp / 128;

  for (int l = 0; l < NLAYER; ++l) {
    // ---- attention ----
    rmsnorm_k<<<M, 256, 0, stream>>>(h, ln_attn + (size_t)l * D, xbf, D);
    gemm_dq<<<mb * (3*D/128), 256, 0, stream>>>(
        xbf, pkQ + (size_t)l*3*D*D/8, qkvS + (size_t)l*3*D*(D/64), qkv,
        mb, 3*D, D, 0, 1);
    lora1<<<dim3(M/4, 3), 256, 0, stream>>>(xbf, qkvA + (size_t)l*3*R*D, t, D);
    lora2<<<dim3(3*D/256, M/8), 256, 0, stream>>>(
        qkv, t, qkvB + (size_t)l*3*D*R, 3*D, 11, 48);
    rope_apply<<<((size_t)M*NHEAD*64 + 255)/256, 256, 0, stream>>>(qkv, cosT, sinT);
    attn_k<<<BATCH*NHEAD, 256, 0, stream>>>(qkv, amask, xbf);
    gemm_dq<<<mb * (D/128) * 4, 256, 0, stream>>>(
        xbf, pkO + (size_t)l*D*D/8, oS + (size_t)l*D*(D/64), h, mb, D, D, 1, 4);
    lora1<<<dim3(M/4, 1), 256, 0, stream>>>(xbf, oA + (size_t)l*R*D, t, D);
    lora2<<<dim3(D/256, M/8), 256, 0, stream>>>(h, t, oB + (size_t)l*D*R, D, 11, 16);

    // ---- MLP ----
    rmsnorm_k<<<M, 256, 0, stream>>>(h, ln_mlp + (size_t)l * D, xbf, D);
    gemm_dq<<<mb * (2*F/128), 256, 0, stream>>>(
        xbf, pkG + (size_t)l*2*F*D/8, guS + (size_t)l*2*F*(D/64), gu,
        mb, 2*F, D, 0, 1);
    lora1<<<dim3(M/4, 2), 256, 0, stream>>>(xbf, guA + (size_t)l*2*R*D, t, D);
    lora2<<<dim3(2*F/256, M/8), 256, 0, stream>>>(
        gu, t, guB + (size_t)l*2*F*R, 2*F, 13, 32);
    silu_mul<<<((size_t)M * F)/256, 256, 0, stream>>>(gu, gbf);
    gemm_dq<<<mb * (D/128) * 4, 256, 0, stream>>>(
        gbf, pkD + (size_t)l*D*F/8, dnS + (size_t)l*D*(F/64), h, mb, D, F, 1, 4);
    lora1<<<dim3(M/4, 1), 256, 0, stream>>>(gbf, dnA + (size_t)l*R*F, t, F);
    lora2<<<dim3(D/256, M/8), 256, 0, stream>>>(h, t, dnB + (size_t)l*D*R, D, 11, 16);
  }
  final_k<<<BATCH, 256, 0, stream>>>(h, amask, ln_fin, out);
}

// Round 5
// 1580.740 us; speedup vs baseline: 2.0663x; 1.4476x over previous
//
#include <hip/hip_runtime.h>
#include <cstdint>
#include <cstddef>

#define M_TOK   1232      // B*S
#define M_PAD   1280
#define D_MODEL 2048
#define F_FFN   8192
#define SEQ     77
#define BATCH   16
#define NHEAD   16
#define LRANK   16
#define NLAYER  2

typedef short bf16x8 __attribute__((ext_vector_type(8)));
typedef float f32x4  __attribute__((ext_vector_type(4)));

__device__ __constant__ float NF4C[16] = {
  -1.0f, -0.6961928009986877f, -0.5250730514526367f, -0.39491748809814453f,
  -0.28444138169288635f, -0.18477343022823334f, -0.09105003625154495f, 0.0f,
  0.07958029955625534f, 0.16093020141124725f, 0.24611230194568634f,
  0.33791524171829224f, 0.44070982933044434f, 0.5626170039176941f,
  0.723855197429657f, 1.0f };

__device__ inline unsigned short f2b(float f) {
  unsigned u = __builtin_bit_cast(unsigned, f);
  u += 0x7FFFu + ((u >> 16) & 1u);   // RNE
  return (unsigned short)(u >> 16);
}
__device__ inline float b2f(unsigned short s) {
  return __builtin_bit_cast(float, ((unsigned)s) << 16);
}

// ---------------------------------------------------------------------------
// Materialize bf16 weights: W[n][k] = bf16(NF4[C[n][k]] * AM[n][k/64])
// Streaming, HBM-bound. 8 elements per thread.
// ---------------------------------------------------------------------------
__global__ __launch_bounds__(256) void mat_w(
    const int* __restrict__ C, const float* __restrict__ AM,
    unsigned short* __restrict__ W, int K, long total8)
{
  __shared__ float tb[16];
  if (threadIdx.x < 16) tb[threadIdx.x] = NF4C[threadIdx.x];
  __syncthreads();
  const int KB = K >> 6;
  for (long i = (long)blockIdx.x * 256 + threadIdx.x; i < total8;
       i += (long)gridDim.x * 256) {
    long e = i << 3;                    // element index (multiple of 8)
    int n = (int)(e / K), k = (int)(e - (long)n * K);
    float am = AM[(size_t)n * KB + (k >> 6)];
    const int4* cp = (const int4*)(C + e);
    int4 a = cp[0], b = cp[1];
    uint4 o;
    o.x = (unsigned)f2b(tb[a.x] * am) | ((unsigned)f2b(tb[a.y] * am) << 16);
    o.y = (unsigned)f2b(tb[a.z] * am) | ((unsigned)f2b(tb[a.w] * am) << 16);
    o.z = (unsigned)f2b(tb[b.x] * am) | ((unsigned)f2b(tb[b.y] * am) << 16);
    o.w = (unsigned)f2b(tb[b.z] * am) | ((unsigned)f2b(tb[b.w] * am) << 16);
    *(uint4*)(W + e) = o;
  }
}

// ---------------------------------------------------------------------------
// bf16 GEMM (m97 pattern): O[M][N] (+)= X[M][K] @ W^T, both operands staged
// via global_load_lds with pre-swizzled source; 128x128 tile, BK=64, 4 waves
// 2x2, wave = 64x64 via 4x4 16x16x32 MFMA, direct C-accumulation.
// One barrier per K-tile; next tile's DMA issued before compute.
// ---------------------------------------------------------------------------
__global__ __launch_bounds__(256, 2) void gemm_bf(
    const unsigned short* __restrict__ X, const unsigned short* __restrict__ W,
    float* __restrict__ O, int mb, int N, int K, int acc_mode, int splitk)
{
  __shared__ __align__(16) unsigned short xs[2][128 * 64];
  __shared__ __align__(16) unsigned short ws[2][128 * 64];

  int tid = threadIdx.x;

  // XCD-chunked bijective swizzle
  int nwg = gridDim.x;
  int q8 = nwg >> 3, r8 = nwg & 7;
  int xcd = blockIdx.x & 7, pos = blockIdx.x >> 3;
  int wgid = (xcd < r8) ? (xcd * (q8 + 1) + pos)
                        : (r8 * (q8 + 1) + (xcd - r8) * q8 + pos);
  int nb = N >> 7;
  int per = mb * nb;
  int slice = wgid / per; int rem = wgid - slice * per;
  int nblk = rem / mb, mblk = rem - nblk * mb;
  int row0 = mblk << 7, col0 = nblk << 7;
  int KBtot = K >> 6, kcnt = KBtot / splitk, kbeg = slice * kcnt;

  int wave = tid >> 6, lane = tid & 63;
  int fr = lane & 15, fg = lane >> 4, s7 = fr & 7;
  int wm = (wave >> 1) * 64, wn = (wave & 1) * 64;
  int xg = lane >> 3;
  int xcol = (((lane & 7) ^ (xg & 7)) << 3);   // pre-swizzled source column

  const unsigned short* Xbase = X + (size_t)row0 * K + (size_t)kbeg * 64;
  const unsigned short* Wbase = W + (size_t)col0 * K + (size_t)kbeg * 64;

  f32x4 accm[4][4];
  #pragma unroll
  for (int i = 0; i < 4; ++i)
    #pragma unroll
    for (int j = 0; j < 4; ++j) accm[i][j] = (f32x4){0.f, 0.f, 0.f, 0.f};

  auto stage = [&](const unsigned short* gbase, unsigned short* dst, int t) {
    const unsigned short* gb = gbase + (size_t)t * 64;
    #pragma unroll
    for (int p2 = 0; p2 < 4; ++p2) {
      int c = wave * 4 + p2;
      const unsigned short* gp = gb + (size_t)(c * 8 + xg) * K + xcol;
      __builtin_amdgcn_global_load_lds(
          (const __attribute__((address_space(1))) unsigned int*)gp,
          (__attribute__((address_space(3))) unsigned int*)(dst + c * 512),
          16, 0, 0);
    }
  };
  auto compute = [&](const unsigned short* xb, const unsigned short* wb) {
    bf16x8 b0[4], b1[4];
    #pragma unroll
    for (int ni = 0; ni < 4; ++ni) {
      const unsigned short* wr = wb + (wn + ni * 16 + fr) * 64;
      b0[ni] = *(const bf16x8*)(wr + ((fg ^ s7) << 3));
      b1[ni] = *(const bf16x8*)(wr + (((4 | fg) ^ s7) << 3));
    }
    #pragma unroll
    for (int mi = 0; mi < 4; ++mi) {
      const unsigned short* xr = xb + (wm + mi * 16 + fr) * 64;
      bf16x8 a0 = *(const bf16x8*)(xr + ((fg ^ s7) << 3));
      bf16x8 a1 = *(const bf16x8*)(xr + (((4 | fg) ^ s7) << 3));
      #pragma unroll
      for (int ni = 0; ni < 4; ++ni) {
        accm[mi][ni] = __builtin_amdgcn_mfma_f32_16x16x32_bf16(
            a0, b0[ni], accm[mi][ni], 0, 0, 0);
        accm[mi][ni] = __builtin_amdgcn_mfma_f32_16x16x32_bf16(
            a1, b1[ni], accm[mi][ni], 0, 0, 0);
      }
    }
  };

  // prologue
  stage(Xbase, &xs[0][0], 0);
  stage(Wbase, &ws[0][0], 0);
  __syncthreads();

  for (int t = 0; t < kcnt; ++t) {
    int cur = t & 1;
    if (t + 1 < kcnt) {
      stage(Xbase, &xs[cur ^ 1][0], t + 1);
      stage(Wbase, &ws[cur ^ 1][0], t + 1);
    }
    compute(&xs[cur][0], &ws[cur][0]);
    __syncthreads();
  }

  // epilogue
  #pragma unroll
  for (int mi = 0; mi < 4; ++mi)
    #pragma unroll
    for (int ni = 0; ni < 4; ++ni) {
      int gm0 = row0 + wm + mi * 16 + fg * 4;
      int gn = col0 + wn + ni * 16 + fr;
      #pragma unroll
      for (int r = 0; r < 4; ++r) {
        int gm = gm0 + r;
        if (gm < M_TOK) {
          size_t idx = (size_t)gm * N + gn;
          float vv = accm[mi][ni][r];
          if (splitk > 1)       atomicAdd(&O[idx], vv);
          else if (acc_mode)    O[idx] += vv;
          else                  O[idx] = vv;
        }
      }
    }
}

// ---------------------------------------------------------------------------
// LoRA stage 1, 4 m-rows per block: T[m][bi*16+g] = sum_k X[m][k]*A[bi][g][k]
__global__ __launch_bounds__(256) void lora1(
    const unsigned short* __restrict__ X, const float* __restrict__ A,
    float* __restrict__ T, int K)
{
  int m0 = blockIdx.x * 4, bi = blockIdx.y, nmat = gridDim.y;
  int g = threadIdx.x >> 4, l16 = threadIdx.x & 15;
  const float* ar = A + (size_t)bi * LRANK * K + (size_t)g * K;
  const unsigned short* x0 = X + (size_t)m0 * K;
  float s0 = 0.f, s1 = 0.f, s2 = 0.f, s3 = 0.f;
  for (int kk = l16 * 4; kk < K; kk += 64) {
    float4 av = *(const float4*)(ar + kk);
    ushort4 v0 = *(const ushort4*)(x0 + kk);
    ushort4 v1 = *(const ushort4*)(x0 + K + kk);
    ushort4 v2 = *(const ushort4*)(x0 + 2 * K + kk);
    ushort4 v3 = *(const ushort4*)(x0 + 3 * K + kk);
    s0 += b2f(v0.x)*av.x + b2f(v0.y)*av.y + b2f(v0.z)*av.z + b2f(v0.w)*av.w;
    s1 += b2f(v1.x)*av.x + b2f(v1.y)*av.y + b2f(v1.z)*av.z + b2f(v1.w)*av.w;
    s2 += b2f(v2.x)*av.x + b2f(v2.y)*av.y + b2f(v2.z)*av.z + b2f(v2.w)*av.w;
    s3 += b2f(v3.x)*av.x + b2f(v3.y)*av.y + b2f(v3.z)*av.z + b2f(v3.w)*av.w;
  }
  #pragma unroll
  for (int off = 8; off; off >>= 1) {
    s0 += __shfl_down(s0, off, 16);
    s1 += __shfl_down(s1, off, 16);
    s2 += __shfl_down(s2, off, 16);
    s3 += __shfl_down(s3, off, 16);
  }
  if (l16 == 0) {
    size_t base = ((size_t)m0 * nmat + bi) * LRANK + g;
    size_t rs = (size_t)nmat * LRANK;
    T[base] = s0; T[base + rs] = s1; T[base + 2*rs] = s2; T[base + 3*rs] = s3;
  }
}

// LoRA stage 2, 8 m-rows per block: O[m][n] += 2*sum_r T[m][(n>>sh)*16+r]*Bm[n][r]
__global__ __launch_bounds__(256) void lora2(
    float* __restrict__ O, const float* __restrict__ T,
    const float* __restrict__ Bm, int N, int sh, int nr)
{
  int m0 = blockIdx.y * 8;
  int n = blockIdx.x * 256 + threadIdx.x;
  __shared__ float ts[8 * 48];
  for (int i = threadIdx.x; i < 8 * nr; i += 256)
    ts[(i / nr) * 48 + (i % nr)] = T[(size_t)(m0 + i / nr) * nr + (i % nr)];
  __syncthreads();
  const float4* br = (const float4*)(Bm + (size_t)n * LRANK);
  float4 b0 = br[0], b1 = br[1], b2 = br[2], b3 = br[3];
  int toff = ((n >> sh) << 4);
  #pragma unroll
  for (int mi = 0; mi < 8; ++mi) {
    const float* tsb = ts + mi * 48 + toff;
    float s = b0.x*tsb[0] + b0.y*tsb[1] + b0.z*tsb[2] + b0.w*tsb[3]
            + b1.x*tsb[4] + b1.y*tsb[5] + b1.z*tsb[6] + b1.w*tsb[7]
            + b2.x*tsb[8] + b2.y*tsb[9] + b2.z*tsb[10] + b2.w*tsb[11]
            + b3.x*tsb[12] + b3.y*tsb[13] + b3.z*tsb[14] + b3.w*tsb[15];
    O[(size_t)(m0 + mi) * N + n] += 2.0f * s;
  }
}

// ---------------------------------------------------------------------------
__global__ __launch_bounds__(256) void rmsnorm_k(
    const float* __restrict__ H, const float* __restrict__ W,
    unsigned short* __restrict__ X, int D)
{
  int m = blockIdx.x;
  const float* hr = H + (size_t)m * D;
  float s = 0.f;
  for (int i = threadIdx.x; i < D; i += 256) { float v = hr[i]; s += v * v; }
  __shared__ float red[4];
  #pragma unroll
  for (int off = 32; off; off >>= 1) s += __shfl_down(s, off, 64);
  if ((threadIdx.x & 63) == 0) red[threadIdx.x >> 6] = s;
  __syncthreads();
  float tot = red[0] + red[1] + red[2] + red[3];
  float inv = rsqrtf(tot / (float)D + 1e-6f);
  for (int i = threadIdx.x; i < D; i += 256)
    X[(size_t)m * D + i] = f2b(hr[i] * inv * W[i]);
}

__global__ void rope_table(float* __restrict__ cosT, float* __restrict__ sinT)
{
  int idx = blockIdx.x * 64 + threadIdx.x;
  if (idx >= SEQ * 64) return;
  int s = idx >> 6, j = idx & 63;
  float inv = powf(10000.0f, -(float)(2 * j) / 128.0f);
  float f = (float)s * inv;
  cosT[idx] = cosf(f);
  sinT[idx] = sinf(f);
}

// QKV packed buffer: row stride 6144; q at +0, k at +2048
__global__ void rope_apply(float* __restrict__ QKV,
                           const float* __restrict__ cosT, const float* __restrict__ sinT)
{
  size_t idx = (size_t)blockIdx.x * 256 + threadIdx.x;
  if (idx >= (size_t)M_TOK * NHEAD * 64) return;
  int j = (int)(idx & 63);
  int h = (int)((idx >> 6) & (NHEAD - 1));
  int m = (int)(idx >> 10);
  int s = m % SEQ;
  float c = cosT[s * 64 + j], sn = sinT[s * 64 + j];
  size_t base = (size_t)m * (3 * D_MODEL) + h * 128;
  float q1 = QKV[base + j], q2 = QKV[base + 64 + j];
  QKV[base + j]      = q1 * c - q2 * sn;
  QKV[base + 64 + j] = q2 * c + q1 * sn;
  size_t kb = base + D_MODEL;
  float k1 = QKV[kb + j], k2 = QKV[kb + 64 + j];
  QKV[kb + j]      = k1 * c - k2 * sn;
  QKV[kb + 64 + j] = k2 * c + k1 * sn;
}

__global__ __launch_bounds__(256) void attn_k(
    const float* __restrict__ QKV, const int* __restrict__ amask,
    unsigned short* __restrict__ O)
{
  int bh = blockIdx.x;
  int b = bh / NHEAD, h = bh % NHEAD;
  __shared__ float sc[SEQ * SEQ];
  const float scale = 0.08838834764831845f;  // 1/sqrt(128)
  const int STR = 3 * D_MODEL;
  for (int idx = threadIdx.x; idx < SEQ * SEQ; idx += 256) {
    int i = idx / SEQ, j = idx % SEQ;
    float val = -1e9f;
    if (j <= i && amask[b * SEQ + j] != 0) {
      const float4* qr = (const float4*)(QKV + (size_t)(b*SEQ+i) * STR + h*128);
      const float4* kr = (const float4*)(QKV + (size_t)(b*SEQ+j) * STR + D_MODEL + h*128);
      float s = 0.f;
      #pragma unroll 8
      for (int d = 0; d < 32; ++d) {
        float4 a = qr[d], c = kr[d];
        s += a.x*c.x + a.y*c.y + a.z*c.z + a.w*c.w;
      }
      val = s * scale;
    }
    sc[idx] = val;
  }
  __syncthreads();
  for (int i = threadIdx.x; i < SEQ; i += 256) {
    float mx = -1e30f;
    for (int j = 0; j < SEQ; ++j) mx = fmaxf(mx, sc[i*SEQ+j]);
    float sum = 0.f;
    for (int j = 0; j < SEQ; ++j) { float e = expf(sc[i*SEQ+j] - mx); sc[i*SEQ+j] = e; sum += e; }
    float inv = 1.0f / sum;
    for (int j = 0; j < SEQ; ++j) sc[i*SEQ+j] *= inv;
  }
  __syncthreads();
  // PV: float4-vectorized over d
  for (int idx = threadIdx.x; idx < SEQ * 32; idx += 256) {
    int i = idx >> 5, d4 = (idx & 31) << 2;
    float4 acc = {0.f, 0.f, 0.f, 0.f};
    for (int j = 0; j < SEQ; ++j) {
      float p = sc[i * SEQ + j];
      float4 v = *(const float4*)(QKV + (size_t)(b*SEQ+j) * STR + 2*D_MODEL + h*128 + d4);
      acc.x += p * v.x; acc.y += p * v.y; acc.z += p * v.z; acc.w += p * v.w;
    }
    unsigned short* op = O + (size_t)(b*SEQ+i) * D_MODEL + h*128 + d4;
    op[0] = f2b(acc.x); op[1] = f2b(acc.y); op[2] = f2b(acc.z); op[3] = f2b(acc.w);
  }
}

__global__ void embed_gather(const float* __restrict__ E, const int* __restrict__ ids,
                             float* __restrict__ H)
{
  size_t idx = (size_t)blockIdx.x * 256 + threadIdx.x;
  int m = (int)(idx / D_MODEL);
  int n = (int)(idx % D_MODEL);
  H[idx] = E[(size_t)ids[m] * D_MODEL + n];
}

// GU packed buffer: row stride 16384; g at +0, up at +8192. Output bf16.
__global__ void silu_mul(const float* __restrict__ GU, unsigned short* __restrict__ GB)
{
  size_t id = (size_t)blockIdx.x * 256 + threadIdx.x;
  int m = (int)(id >> 13), n = (int)(id & (F_FFN - 1));
  float g = GU[(size_t)m * 2 * F_FFN + n];
  float u = GU[(size_t)m * 2 * F_FFN + F_FFN + n];
  float sig = 1.0f / (1.0f + expf(-g));
  GB[id] = f2b(g * sig * u);
}

__global__ __launch_bounds__(256) void final_k(
    const float* __restrict__ H, const int* __restrict__ amask,
    const float* __restrict__ W, float* __restrict__ out)
{
  int b = blockIdx.x;
  __shared__ int len;
  if (threadIdx.x == 0) {
    int s = 0;
    for (int j = 0; j < SEQ; ++j) s += amask[b * SEQ + j];
    len = s - 1;
  }
  __syncthreads();
  const float* hr = H + ((size_t)(b * SEQ + len) * D_MODEL);
  float s = 0.f;
  for (int i = threadIdx.x; i < D_MODEL; i += 256) { float v = hr[i]; s += v * v; }
  __shared__ float red[4];
  #pragma unroll
  for (int off = 32; off; off >>= 1) s += __shfl_down(s, off, 64);
  if ((threadIdx.x & 63) == 0) red[threadIdx.x >> 6] = s;
  __syncthreads();
  float tot = red[0] + red[1] + red[2] + red[3];
  float inv = rsqrtf(tot / (float)D_MODEL + 1e-6f);
  for (int i = threadIdx.x; i < D_MODEL; i += 256)
    out[(size_t)b * D_MODEL + i] = hr[i] * inv * W[i];
}

// ---------------------------------------------------------------------------
extern "C" void kernel_launch(void* const* d_in, const int* in_sizes, int n_in,
                              void* d_out, int out_size, void* d_ws, size_t ws_size,
                              hipStream_t stream) {
  const int*   ids     = (const int*)d_in[0];
  const int*   amask   = (const int*)d_in[1];
  const float* embed   = (const float*)d_in[2];
  const float* ln_attn = (const float*)d_in[3];
  const float* ln_mlp  = (const float*)d_in[4];
  const float* ln_fin  = (const float*)d_in[5];
  const int*   qkvC    = (const int*)d_in[6];
  const float* qkvS    = (const float*)d_in[7];
  const float* qkvA    = (const float*)d_in[8];
  const float* qkvB    = (const float*)d_in[9];
  const int*   oC      = (const int*)d_in[10];
  const float* oS      = (const float*)d_in[11];
  const float* oA      = (const float*)d_in[12];
  const float* oB      = (const float*)d_in[13];
  const int*   guC     = (const int*)d_in[14];
  const float* guS     = (const float*)d_in[15];
  const float* guA     = (const float*)d_in[16];
  const float* guB     = (const float*)d_in[17];
  const int*   dnC     = (const int*)d_in[18];
  const float* dnS     = (const float*)d_in[19];
  const float* dnA     = (const float*)d_in[20];
  const float* dnB     = (const float*)d_in[21];
  float* out = (float*)d_out;

  const int M = M_TOK, Mp = M_PAD, D = D_MODEL, F = F_FFN, R = LRANK;
  float* p = (float*)d_ws;
  float* h    = p; p += (size_t)Mp * D;
  float* qkv  = p; p += (size_t)Mp * 3 * D;   // also reused as gbf (bf16) later
  float* gu   = p; p += (size_t)Mp * 2 * F;
  float* t    = p; p += (size_t)Mp * 48;
  float* cosT = p; p += SEQ * 64;
  float* sinT = p; p += SEQ * 64;
  unsigned short* xbf = (unsigned short*)p; p += (size_t)Mp * D / 2;
  unsigned short* gbf = (unsigned short*)qkv;   // Mp*F ushorts <= Mp*3*D floats
  unsigned short* wbuf = (unsigned short*)p;    // bf16 weight buffer, max 2*F*D elems
  p += (size_t)2 * F * D / 2;

  rope_table<<<(SEQ*64 + 63)/64, 64, 0, stream>>>(cosT, sinT);
  embed_gather<<<(M * D)/256, 256, 0, stream>>>(embed, ids, h);

  const int mb = Mp / 128;

  for (int l = 0; l < NLAYER; ++l) {
    // ---- attention ----
    rmsnorm_k<<<M, 256, 0, stream>>>(h, ln_attn + (size_t)l * D, xbf, D);
    mat_w<<<4096, 256, 0, stream>>>(qkvC + (size_t)l*3*D*D, qkvS + (size_t)l*3*D*(D/64),
                                    wbuf, D, (long)3*D*D/8);
    gemm_bf<<<mb * (3*D/128), 256, 0, stream>>>(xbf, wbuf, qkv, mb, 3*D, D, 0, 1);
    lora1<<<dim3(M/4, 3), 256, 0, stream>>>(xbf, qkvA + (size_t)l*3*R*D, t, D);
    lora2<<<dim3(3*D/256, M/8), 256, 0, stream>>>(
        qkv, t, qkvB + (size_t)l*3*D*R, 3*D, 11, 48);
    rope_apply<<<((size_t)M*NHEAD*64 + 255)/256, 256, 0, stream>>>(qkv, cosT, sinT);
    attn_k<<<BATCH*NHEAD, 256, 0, stream>>>(qkv, amask, xbf);
    mat_w<<<2048, 256, 0, stream>>>(oC + (size_t)l*D*D, oS + (size_t)l*D*(D/64),
                                    wbuf, D, (long)D*D/8);
    gemm_bf<<<mb * (D/128) * 8, 256, 0, stream>>>(xbf, wbuf, h, mb, D, D, 1, 8);
    lora1<<<dim3(M/4, 1), 256, 0, stream>>>(xbf, oA + (size_t)l*R*D, t, D);
    lora2<<<dim3(D/256, M/8), 256, 0, stream>>>(h, t, oB + (size_t)l*D*R, D, 11, 16);

    // ---- MLP ----
    rmsnorm_k<<<M, 256, 0, stream>>>(h, ln_mlp + (size_t)l * D, xbf, D);
    mat_w<<<4096, 256, 0, stream>>>(guC + (size_t)l*2*F*D, guS + (size_t)l*2*F*(D/64),
                                    wbuf, D, (long)2*F*D/8);
    gemm_bf<<<mb * (2*F/128), 256, 0, stream>>>(xbf, wbuf, gu, mb, 2*F, D, 0, 1);
    lora1<<<dim3(M/4, 2), 256, 0, stream>>>(xbf, guA + (size_t)l*2*R*D, t, D);
    lora2<<<dim3(2*F/256, M/8), 256, 0, stream>>>(
        gu, t, guB + (size_t)l*2*F*R, 2*F, 13, 32);
    silu_mul<<<((size_t)M * F)/256, 256, 0, stream>>>(gu, gbf);
    mat_w<<<4096, 256, 0, stream>>>(dnC + (size_t)l*D*F, dnS + (size_t)l*D*(F/64),
                                    wbuf, F, (long)D*F/8);
    gemm_bf<<<mb * (D/128) * 8, 256, 0, stream>>>(gbf, wbuf, h, mb, D, F, 1, 8);
    lora1<<<dim3(M/4, 1), 256, 0, stream>>>(gbf, dnA + (size_t)l*R*F, t, F);
    lora2<<<dim3(D/256, M/8), 256, 0, stream>>>(h, t, dnB + (size_t)l*D*R, D, 11, 16);
  }
  final_k<<<BATCH, 256, 0, stream>>>(h, amask, ln_fin, out);
}

// Round 6
// 1448.142 us; speedup vs baseline: 2.2555x; 1.0916x over previous
//
#include <hip/hip_runtime.h>
#include <cstdint>
#include <cstddef>

#define M_TOK   1232      // B*S
#define M_PAD   1280
#define D_MODEL 2048
#define F_FFN   8192
#define SEQ     77
#define BATCH   16
#define NHEAD   16
#define LRANK   16
#define NLAYER  2
#define ATILE   16

typedef short bf16x8 __attribute__((ext_vector_type(8)));
typedef float f32x4  __attribute__((ext_vector_type(4)));

__device__ __constant__ float NF4C[16] = {
  -1.0f, -0.6961928009986877f, -0.5250730514526367f, -0.39491748809814453f,
  -0.28444138169288635f, -0.18477343022823334f, -0.09105003625154495f, 0.0f,
  0.07958029955625534f, 0.16093020141124725f, 0.24611230194568634f,
  0.33791524171829224f, 0.44070982933044434f, 0.5626170039176941f,
  0.723855197429657f, 1.0f };

__device__ inline unsigned short f2b(float f) {
  unsigned u = __builtin_bit_cast(unsigned, f);
  u += 0x7FFFu + ((u >> 16) & 1u);   // RNE
  return (unsigned short)(u >> 16);
}
__device__ inline float b2f(unsigned short s) {
  return __builtin_bit_cast(float, ((unsigned)s) << 16);
}

// ---------------------------------------------------------------------------
// Materialize bf16 weights: W[n][k] = bf16(NF4[C[n][k]] * AM[n][k/64])
// ---------------------------------------------------------------------------
__global__ __launch_bounds__(256) void mat_w(
    const int* __restrict__ C, const float* __restrict__ AM,
    unsigned short* __restrict__ W, int K, long total8)
{
  __shared__ float tb[16];
  if (threadIdx.x < 16) tb[threadIdx.x] = NF4C[threadIdx.x];
  __syncthreads();
  const int KB = K >> 6;
  for (long i = (long)blockIdx.x * 256 + threadIdx.x; i < total8;
       i += (long)gridDim.x * 256) {
    long e = i << 3;                    // element index (multiple of 8)
    int n = (int)(e / K), k = (int)(e - (long)n * K);
    float am = AM[(size_t)n * KB + (k >> 6)];
    const int4* cp = (const int4*)(C + e);
    int4 a = cp[0], b = cp[1];
    uint4 o;
    o.x = (unsigned)f2b(tb[a.x] * am) | ((unsigned)f2b(tb[a.y] * am) << 16);
    o.y = (unsigned)f2b(tb[a.z] * am) | ((unsigned)f2b(tb[a.w] * am) << 16);
    o.z = (unsigned)f2b(tb[b.x] * am) | ((unsigned)f2b(tb[b.y] * am) << 16);
    o.w = (unsigned)f2b(tb[b.z] * am) | ((unsigned)f2b(tb[b.w] * am) << 16);
    *(uint4*)(W + e) = o;
  }
}

// ---------------------------------------------------------------------------
// bf16 GEMM (m97 pattern) + optional fused LoRA-2 epilogue (splitk==1 only).
// O[M][N] (+)= X @ W^T (+ 2 * T @ Bm^T restricted to this block's lora mat).
// ---------------------------------------------------------------------------
__global__ __launch_bounds__(256, 2) void gemm_bf(
    const unsigned short* __restrict__ X, const unsigned short* __restrict__ W,
    float* __restrict__ O, int mb, int N, int K, int acc_mode, int splitk,
    const float* __restrict__ T, const float* __restrict__ Bm, int sh, int nr)
{
  __shared__ __align__(16) unsigned short xs[2][128 * 64];
  __shared__ __align__(16) unsigned short ws[2][128 * 64];

  int tid = threadIdx.x;

  // XCD-chunked bijective swizzle
  int nwg = gridDim.x;
  int q8 = nwg >> 3, r8 = nwg & 7;
  int xcd = blockIdx.x & 7, pos = blockIdx.x >> 3;
  int wgid = (xcd < r8) ? (xcd * (q8 + 1) + pos)
                        : (r8 * (q8 + 1) + (xcd - r8) * q8 + pos);
  int nb = N >> 7;
  int per = mb * nb;
  int slice = wgid / per; int rem = wgid - slice * per;
  int nblk = rem / mb, mblk = rem - nblk * mb;
  int row0 = mblk << 7, col0 = nblk << 7;
  int KBtot = K >> 6, kcnt = KBtot / splitk, kbeg = slice * kcnt;

  int wave = tid >> 6, lane = tid & 63;
  int fr = lane & 15, fg = lane >> 4, s7 = fr & 7;
  int wm = (wave >> 1) * 64, wn = (wave & 1) * 64;
  int xg = lane >> 3;
  int xcol = (((lane & 7) ^ (xg & 7)) << 3);

  const unsigned short* Xbase = X + (size_t)row0 * K + (size_t)kbeg * 64;
  const unsigned short* Wbase = W + (size_t)col0 * K + (size_t)kbeg * 64;

  f32x4 accm[4][4];
  #pragma unroll
  for (int i = 0; i < 4; ++i)
    #pragma unroll
    for (int j = 0; j < 4; ++j) accm[i][j] = (f32x4){0.f, 0.f, 0.f, 0.f};

  auto stage = [&](const unsigned short* gbase, unsigned short* dst, int t) {
    const unsigned short* gb = gbase + (size_t)t * 64;
    #pragma unroll
    for (int p2 = 0; p2 < 4; ++p2) {
      int c = wave * 4 + p2;
      const unsigned short* gp = gb + (size_t)(c * 8 + xg) * K + xcol;
      __builtin_amdgcn_global_load_lds(
          (const __attribute__((address_space(1))) unsigned int*)gp,
          (__attribute__((address_space(3))) unsigned int*)(dst + c * 512),
          16, 0, 0);
    }
  };
  auto compute = [&](const unsigned short* xb, const unsigned short* wb) {
    bf16x8 b0[4], b1[4];
    #pragma unroll
    for (int ni = 0; ni < 4; ++ni) {
      const unsigned short* wr = wb + (wn + ni * 16 + fr) * 64;
      b0[ni] = *(const bf16x8*)(wr + ((fg ^ s7) << 3));
      b1[ni] = *(const bf16x8*)(wr + (((4 | fg) ^ s7) << 3));
    }
    #pragma unroll
    for (int mi = 0; mi < 4; ++mi) {
      const unsigned short* xr = xb + (wm + mi * 16 + fr) * 64;
      bf16x8 a0 = *(const bf16x8*)(xr + ((fg ^ s7) << 3));
      bf16x8 a1 = *(const bf16x8*)(xr + (((4 | fg) ^ s7) << 3));
      #pragma unroll
      for (int ni = 0; ni < 4; ++ni) {
        accm[mi][ni] = __builtin_amdgcn_mfma_f32_16x16x32_bf16(
            a0, b0[ni], accm[mi][ni], 0, 0, 0);
        accm[mi][ni] = __builtin_amdgcn_mfma_f32_16x16x32_bf16(
            a1, b1[ni], accm[mi][ni], 0, 0, 0);
      }
    }
  };

  // prologue
  stage(Xbase, &xs[0][0], 0);
  stage(Wbase, &ws[0][0], 0);
  __syncthreads();

  for (int t = 0; t < kcnt; ++t) {
    int cur = t & 1;
    if (t + 1 < kcnt) {
      stage(Xbase, &xs[cur ^ 1][0], t + 1);
      stage(Wbase, &ws[cur ^ 1][0], t + 1);
    }
    compute(&xs[cur][0], &ws[cur][0]);
    __syncthreads();
  }

  // optional fused LoRA-2: stage T[128][16], Bm[128][16] into (free) LDS
  float* Tt = (float*)&xs[0][0];
  float* Bt = (float*)&ws[0][0];
  if (T) {
    int toff = (col0 >> sh) << 4;
    for (int idx = tid; idx < 128 * 16; idx += 256) {
      int rr = idx >> 4, c = idx & 15;
      int gm = row0 + rr;
      Tt[idx] = (gm < M_TOK) ? T[(size_t)gm * nr + toff + c] : 0.f;
      Bt[idx] = Bm[(size_t)(col0 + rr) * LRANK + c];
    }
    __syncthreads();
  }

  // epilogue
  #pragma unroll
  for (int mi = 0; mi < 4; ++mi)
    #pragma unroll
    for (int ni = 0; ni < 4; ++ni) {
      int gm0 = row0 + wm + mi * 16 + fg * 4;
      int gnl = wn + ni * 16 + fr;
      int gn = col0 + gnl;
      #pragma unroll
      for (int r = 0; r < 4; ++r) {
        int gm = gm0 + r;
        if (gm < M_TOK) {
          size_t idx = (size_t)gm * N + gn;
          float vv = accm[mi][ni][r];
          if (T) {
            const float* tr = Tt + (wm + mi * 16 + fg * 4 + r) * 16;
            const float* br = Bt + gnl * 16;
            float s = 0.f;
            #pragma unroll
            for (int c = 0; c < 16; ++c) s += tr[c] * br[c];
            vv += 2.0f * s;
          }
          if (splitk > 1)       atomicAdd(&O[idx], vv);
          else if (acc_mode)    O[idx] += vv;
          else                  O[idx] = vv;
        }
      }
    }
}

// ---------------------------------------------------------------------------
// LoRA stage 1, 4 m-rows per block: T[m][bi*16+g] = sum_k X[m][k]*A[bi][g][k]
__global__ __launch_bounds__(256) void lora1(
    const unsigned short* __restrict__ X, const float* __restrict__ A,
    float* __restrict__ T, int K)
{
  int m0 = blockIdx.x * 4, bi = blockIdx.y, nmat = gridDim.y;
  int g = threadIdx.x >> 4, l16 = threadIdx.x & 15;
  const float* ar = A + (size_t)bi * LRANK * K + (size_t)g * K;
  const unsigned short* x0 = X + (size_t)m0 * K;
  float s0 = 0.f, s1 = 0.f, s2 = 0.f, s3 = 0.f;
  for (int kk = l16 * 4; kk < K; kk += 64) {
    float4 av = *(const float4*)(ar + kk);
    ushort4 v0 = *(const ushort4*)(x0 + kk);
    ushort4 v1 = *(const ushort4*)(x0 + K + kk);
    ushort4 v2 = *(const ushort4*)(x0 + 2 * K + kk);
    ushort4 v3 = *(const ushort4*)(x0 + 3 * K + kk);
    s0 += b2f(v0.x)*av.x + b2f(v0.y)*av.y + b2f(v0.z)*av.z + b2f(v0.w)*av.w;
    s1 += b2f(v1.x)*av.x + b2f(v1.y)*av.y + b2f(v1.z)*av.z + b2f(v1.w)*av.w;
    s2 += b2f(v2.x)*av.x + b2f(v2.y)*av.y + b2f(v2.z)*av.z + b2f(v2.w)*av.w;
    s3 += b2f(v3.x)*av.x + b2f(v3.y)*av.y + b2f(v3.z)*av.z + b2f(v3.w)*av.w;
  }
  #pragma unroll
  for (int off = 8; off; off >>= 1) {
    s0 += __shfl_down(s0, off, 16);
    s1 += __shfl_down(s1, off, 16);
    s2 += __shfl_down(s2, off, 16);
    s3 += __shfl_down(s3, off, 16);
  }
  if (l16 == 0) {
    size_t base = ((size_t)m0 * nmat + bi) * LRANK + g;
    size_t rs = (size_t)nmat * LRANK;
    T[base] = s0; T[base + rs] = s1; T[base + 2*rs] = s2; T[base + 3*rs] = s3;
  }
}

// LoRA stage 2 (separate path for split-K GEMMs), 8 m-rows per block
__global__ __launch_bounds__(256) void lora2(
    float* __restrict__ O, const float* __restrict__ T,
    const float* __restrict__ Bm, int N, int sh, int nr)
{
  int m0 = blockIdx.y * 8;
  int n = blockIdx.x * 256 + threadIdx.x;
  __shared__ float ts[8 * 48];
  for (int i = threadIdx.x; i < 8 * nr; i += 256)
    ts[(i / nr) * 48 + (i % nr)] = T[(size_t)(m0 + i / nr) * nr + (i % nr)];
  __syncthreads();
  const float4* br = (const float4*)(Bm + (size_t)n * LRANK);
  float4 b0 = br[0], b1 = br[1], b2 = br[2], b3 = br[3];
  int toff = ((n >> sh) << 4);
  #pragma unroll
  for (int mi = 0; mi < 8; ++mi) {
    const float* tsb = ts + mi * 48 + toff;
    float s = b0.x*tsb[0] + b0.y*tsb[1] + b0.z*tsb[2] + b0.w*tsb[3]
            + b1.x*tsb[4] + b1.y*tsb[5] + b1.z*tsb[6] + b1.w*tsb[7]
            + b2.x*tsb[8] + b2.y*tsb[9] + b2.z*tsb[10] + b2.w*tsb[11]
            + b3.x*tsb[12] + b3.y*tsb[13] + b3.z*tsb[14] + b3.w*tsb[15];
    O[(size_t)(m0 + mi) * N + n] += 2.0f * s;
  }
}

// ---------------------------------------------------------------------------
__global__ __launch_bounds__(256) void rmsnorm_k(
    const float* __restrict__ H, const float* __restrict__ W,
    unsigned short* __restrict__ X, int D)
{
  int m = blockIdx.x;
  const float* hr = H + (size_t)m * D;
  float s = 0.f;
  for (int i = threadIdx.x; i < D; i += 256) { float v = hr[i]; s += v * v; }
  __shared__ float red[4];
  #pragma unroll
  for (int off = 32; off; off >>= 1) s += __shfl_down(s, off, 64);
  if ((threadIdx.x & 63) == 0) red[threadIdx.x >> 6] = s;
  __syncthreads();
  float tot = red[0] + red[1] + red[2] + red[3];
  float inv = rsqrtf(tot / (float)D + 1e-6f);
  for (int i = threadIdx.x; i < D; i += 256)
    X[(size_t)m * D + i] = f2b(hr[i] * inv * W[i]);
}

__global__ void rope_table(float* __restrict__ cosT, float* __restrict__ sinT)
{
  int idx = blockIdx.x * 64 + threadIdx.x;
  if (idx >= SEQ * 64) return;
  int s = idx >> 6, j = idx & 63;
  float inv = powf(10000.0f, -(float)(2 * j) / 128.0f);
  float f = (float)s * inv;
  cosT[idx] = cosf(f);
  sinT[idx] = sinf(f);
}

// QKV packed buffer: row stride 6144; q at +0, k at +2048
__global__ void rope_apply(float* __restrict__ QKV,
                           const float* __restrict__ cosT, const float* __restrict__ sinT)
{
  size_t idx = (size_t)blockIdx.x * 256 + threadIdx.x;
  if (idx >= (size_t)M_TOK * NHEAD * 64) return;
  int j = (int)(idx & 63);
  int h = (int)((idx >> 6) & (NHEAD - 1));
  int m = (int)(idx >> 10);
  int s = m % SEQ;
  float c = cosT[s * 64 + j], sn = sinT[s * 64 + j];
  size_t base = (size_t)m * (3 * D_MODEL) + h * 128;
  float q1 = QKV[base + j], q2 = QKV[base + 64 + j];
  QKV[base + j]      = q1 * c - q2 * sn;
  QKV[base + 64 + j] = q2 * c + q1 * sn;
  size_t kb = base + D_MODEL;
  float k1 = QKV[kb + j], k2 = QKV[kb + 64 + j];
  QKV[kb + j]      = k1 * c - k2 * sn;
  QKV[kb + 64 + j] = k2 * c + k1 * sn;
}

// ---------------------------------------------------------------------------
// Attention: grid (B*H, 5 row-tiles of 16). K staged in LDS (pad 132),
// wave-parallel softmax, coalesced PV from L2.
// ---------------------------------------------------------------------------
__global__ __launch_bounds__(256) void attn_k(
    const float* __restrict__ QKV, const int* __restrict__ amask,
    unsigned short* __restrict__ O)
{
  int bh = blockIdx.x, it = blockIdx.y;
  int b = bh >> 4, h = bh & (NHEAD - 1);
  const int STR = 3 * D_MODEL;
  __shared__ float ks[SEQ * 132];
  __shared__ float sc[ATILE * 80];
  __shared__ int am[SEQ];
  const float scale = 0.08838834764831845f;  // 1/sqrt(128)

  const float* Kbase = QKV + (size_t)(b * SEQ) * STR + D_MODEL + h * 128;
  for (int idx = threadIdx.x; idx < SEQ * 32; idx += 256) {
    int j = idx >> 5, d4 = (idx & 31) << 2;
    *(float4*)(ks + j * 132 + d4) = *(const float4*)(Kbase + (size_t)j * STR + d4);
  }
  for (int j = threadIdx.x; j < SEQ; j += 256) am[j] = amask[b * SEQ + j];
  __syncthreads();

  int wave = threadIdx.x >> 6, lane = threadIdx.x & 63;
  #pragma unroll
  for (int r = 0; r < 4; ++r) {
    int il = wave * 4 + r;
    int i = it * ATILE + il;
    if (i < SEQ) {
      const float4* qr = (const float4*)(QKV + (size_t)(b * SEQ + i) * STR + h * 128);
      int j1 = lane, j2 = lane + 64;
      float v1 = -1e9f, v2 = -1e9f;
      if (j1 <= i && am[j1]) {
        const float4* kr = (const float4*)(ks + j1 * 132);
        float s = 0.f;
        #pragma unroll 8
        for (int d = 0; d < 32; ++d) {
          float4 a = qr[d], c = kr[d];
          s += a.x*c.x + a.y*c.y + a.z*c.z + a.w*c.w;
        }
        v1 = s * scale;
      }
      if (j2 < SEQ && j2 <= i && am[j2]) {
        const float4* kr = (const float4*)(ks + j2 * 132);
        float s = 0.f;
        #pragma unroll 8
        for (int d = 0; d < 32; ++d) {
          float4 a = qr[d], c = kr[d];
          s += a.x*c.x + a.y*c.y + a.z*c.z + a.w*c.w;
        }
        v2 = s * scale;
      }
      float mx = fmaxf(v1, v2);
      #pragma unroll
      for (int off = 32; off; off >>= 1) mx = fmaxf(mx, __shfl_xor(mx, off));
      float e1 = __expf(v1 - mx);
      float e2 = (j2 < SEQ) ? __expf(v2 - mx) : 0.f;
      float sum = e1 + e2;
      #pragma unroll
      for (int off = 32; off; off >>= 1) sum += __shfl_xor(sum, off);
      float inv = 1.0f / sum;
      sc[il * 80 + j1] = e1 * inv;
      if (j2 < SEQ) sc[il * 80 + j2] = e2 * inv;
    }
  }
  __syncthreads();

  const float* Vbase = QKV + (size_t)(b * SEQ) * STR + 2 * D_MODEL + h * 128;
  for (int idx = threadIdx.x; idx < ATILE * 32; idx += 256) {
    int il = idx >> 5, d4 = (idx & 31) << 2;
    int i = it * ATILE + il;
    if (i >= SEQ) continue;
    float4 acc = {0.f, 0.f, 0.f, 0.f};
    const float* sr = sc + il * 80;
    for (int j = 0; j < SEQ; ++j) {
      float pp = sr[j];
      float4 v = *(const float4*)(Vbase + (size_t)j * STR + d4);
      acc.x += pp * v.x; acc.y += pp * v.y; acc.z += pp * v.z; acc.w += pp * v.w;
    }
    unsigned short* op = O + (size_t)(b * SEQ + i) * D_MODEL + h * 128 + d4;
    op[0] = f2b(acc.x); op[1] = f2b(acc.y); op[2] = f2b(acc.z); op[3] = f2b(acc.w);
  }
}

__global__ void embed_gather(const float* __restrict__ E, const int* __restrict__ ids,
                             float* __restrict__ H)
{
  size_t idx = (size_t)blockIdx.x * 256 + threadIdx.x;
  int m = (int)(idx / D_MODEL);
  int n = (int)(idx % D_MODEL);
  H[idx] = E[(size_t)ids[m] * D_MODEL + n];
}

// GU packed buffer: row stride 16384; g at +0, up at +8192. Output bf16.
__global__ void silu_mul(const float* __restrict__ GU, unsigned short* __restrict__ GB)
{
  size_t id = (size_t)blockIdx.x * 256 + threadIdx.x;
  int m = (int)(id >> 13), n = (int)(id & (F_FFN - 1));
  float g = GU[(size_t)m * 2 * F_FFN + n];
  float u = GU[(size_t)m * 2 * F_FFN + F_FFN + n];
  float sig = 1.0f / (1.0f + expf(-g));
  GB[id] = f2b(g * sig * u);
}

__global__ __launch_bounds__(256) void final_k(
    const float* __restrict__ H, const int* __restrict__ amask,
    const float* __restrict__ W, float* __restrict__ out)
{
  int b = blockIdx.x;
  __shared__ int len;
  if (threadIdx.x == 0) {
    int s = 0;
    for (int j = 0; j < SEQ; ++j) s += amask[b * SEQ + j];
    len = s - 1;
  }
  __syncthreads();
  const float* hr = H + ((size_t)(b * SEQ + len) * D_MODEL);
  float s = 0.f;
  for (int i = threadIdx.x; i < D_MODEL; i += 256) { float v = hr[i]; s += v * v; }
  __shared__ float red[4];
  #pragma unroll
  for (int off = 32; off; off >>= 1) s += __shfl_down(s, off, 64);
  if ((threadIdx.x & 63) == 0) red[threadIdx.x >> 6] = s;
  __syncthreads();
  float tot = red[0] + red[1] + red[2] + red[3];
  float inv = rsqrtf(tot / (float)D_MODEL + 1e-6f);
  for (int i = threadIdx.x; i < D_MODEL; i += 256)
    out[(size_t)b * D_MODEL + i] = hr[i] * inv * W[i];
}

// ---------------------------------------------------------------------------
extern "C" void kernel_launch(void* const* d_in, const int* in_sizes, int n_in,
                              void* d_out, int out_size, void* d_ws, size_t ws_size,
                              hipStream_t stream) {
  const int*   ids     = (const int*)d_in[0];
  const int*   amask   = (const int*)d_in[1];
  const float* embed   = (const float*)d_in[2];
  const float* ln_attn = (const float*)d_in[3];
  const float* ln_mlp  = (const float*)d_in[4];
  const float* ln_fin  = (const float*)d_in[5];
  const int*   qkvC    = (const int*)d_in[6];
  const float* qkvS    = (const float*)d_in[7];
  const float* qkvA    = (const float*)d_in[8];
  const float* qkvB    = (const float*)d_in[9];
  const int*   oC      = (const int*)d_in[10];
  const float* oS      = (const float*)d_in[11];
  const float* oA      = (const float*)d_in[12];
  const float* oB      = (const float*)d_in[13];
  const int*   guC     = (const int*)d_in[14];
  const float* guS     = (const float*)d_in[15];
  const float* guA     = (const float*)d_in[16];
  const float* guB     = (const float*)d_in[17];
  const int*   dnC     = (const int*)d_in[18];
  const float* dnS     = (const float*)d_in[19];
  const float* dnA     = (const float*)d_in[20];
  const float* dnB     = (const float*)d_in[21];
  float* out = (float*)d_out;

  const int M = M_TOK, Mp = M_PAD, D = D_MODEL, F = F_FFN, R = LRANK;
  float* p = (float*)d_ws;
  float* h    = p; p += (size_t)Mp * D;
  float* qkv  = p; p += (size_t)Mp * 3 * D;   // also reused as gbf (bf16) later
  float* gu   = p; p += (size_t)Mp * 2 * F;
  float* t    = p; p += (size_t)Mp * 48;
  float* cosT = p; p += SEQ * 64;
  float* sinT = p; p += SEQ * 64;
  unsigned short* xbf = (unsigned short*)p; p += (size_t)Mp * D / 2;
  unsigned short* gbf = (unsigned short*)qkv;   // Mp*F ushorts <= Mp*3*D floats
  unsigned short* wbuf = (unsigned short*)p;    // bf16 weight buffer, max 2*F*D elems
  p += (size_t)2 * F * D / 2;

  rope_table<<<(SEQ*64 + 63)/64, 64, 0, stream>>>(cosT, sinT);
  embed_gather<<<(M * D)/256, 256, 0, stream>>>(embed, ids, h);

  const int mb = Mp / 128;

  for (int l = 0; l < NLAYER; ++l) {
    // ---- attention ----
    rmsnorm_k<<<M, 256, 0, stream>>>(h, ln_attn + (size_t)l * D, xbf, D);
    lora1<<<dim3(M/4, 3), 256, 0, stream>>>(xbf, qkvA + (size_t)l*3*R*D, t, D);
    mat_w<<<4096, 256, 0, stream>>>(qkvC + (size_t)l*3*D*D, qkvS + (size_t)l*3*D*(D/64),
                                    wbuf, D, (long)3*D*D/8);
    gemm_bf<<<mb * (3*D/128), 256, 0, stream>>>(
        xbf, wbuf, qkv, mb, 3*D, D, 0, 1,
        t, qkvB + (size_t)l*3*D*R, 11, 48);
    rope_apply<<<((size_t)M*NHEAD*64 + 255)/256, 256, 0, stream>>>(qkv, cosT, sinT);
    attn_k<<<dim3(BATCH*NHEAD, (SEQ + ATILE - 1)/ATILE), 256, 0, stream>>>(qkv, amask, xbf);
    mat_w<<<2048, 256, 0, stream>>>(oC + (size_t)l*D*D, oS + (size_t)l*D*(D/64),
                                    wbuf, D, (long)D*D/8);
    gemm_bf<<<mb * (D/128) * 8, 256, 0, stream>>>(
        xbf, wbuf, h, mb, D, D, 1, 8, nullptr, nullptr, 0, 0);
    lora1<<<dim3(M/4, 1), 256, 0, stream>>>(xbf, oA + (size_t)l*R*D, t, D);
    lora2<<<dim3(D/256, M/8), 256, 0, stream>>>(h, t, oB + (size_t)l*D*R, D, 11, 16);

    // ---- MLP ----
    rmsnorm_k<<<M, 256, 0, stream>>>(h, ln_mlp + (size_t)l * D, xbf, D);
    lora1<<<dim3(M/4, 2), 256, 0, stream>>>(xbf, guA + (size_t)l*2*R*D, t, D);
    mat_w<<<4096, 256, 0, stream>>>(guC + (size_t)l*2*F*D, guS + (size_t)l*2*F*(D/64),
                                    wbuf, D, (long)2*F*D/8);
    gemm_bf<<<mb * (2*F/128), 256, 0, stream>>>(
        xbf, wbuf, gu, mb, 2*F, D, 0, 1,
        t, guB + (size_t)l*2*F*R, 13, 32);
    silu_mul<<<((size_t)M * F)/256, 256, 0, stream>>>(gu, gbf);
    mat_w<<<4096, 256, 0, stream>>>(dnC + (size_t)l*D*F, dnS + (size_t)l*D*(F/64),
                                    wbuf, F, (long)D*F/8);
    gemm_bf<<<mb * (D/128) * 8, 256, 0, stream>>>(
        gbf, wbuf, h, mb, D, F, 1, 8, nullptr, nullptr, 0, 0);
    lora1<<<dim3(M/4, 1), 256, 0, stream>>>(gbf, dnA + (size_t)l*R*F, t, F);
    lora2<<<dim3(D/256, M/8), 256, 0, stream>>>(h, t, dnB + (size_t)l*D*R, D, 11, 16);
  }
  final_k<<<BATCH, 256, 0, stream>>>(h, amask, ln_fin, out);
}